// Round 3
// baseline (805.705 us; speedup 1.0000x reference)
//
#include <hip/hip_runtime.h>
#include <math.h>

#define T_SEQ 2048
#define NHQ 32
#define NG 2
#define HD 64
#define CSTRIDE 16
#define SCALE 0.125f
#define KVGW 384  // fused k|v|gate row width: 128 k + 128 v + 3 gate + pad

typedef __attribute__((ext_vector_type(8))) short short8_t;
typedef __attribute__((ext_vector_type(4))) short short4_t;
typedef __attribute__((ext_vector_type(4))) float f32x4;

__device__ __forceinline__ ushort f2bf(float x) {  // round-to-nearest-even
  union { float f; unsigned u; } c; c.f = x;
  unsigned r = c.u + 0x7fff + ((c.u >> 16) & 1);
  return (ushort)(r >> 16);
}
__device__ __forceinline__ short pbf(float x) {  // cheap round-half-up (x>=0)
  union { float f; unsigned u; } c; c.f = x;
  return (short)((c.u + 0x8000u) >> 16);
}
__device__ __forceinline__ float bf2f(ushort u) {
  union { unsigned u; float f; } c; c.u = ((unsigned)u) << 16;
  return c.f;
}

__device__ __forceinline__ void glds16(const ushort* g, ushort* l) {
  __builtin_amdgcn_global_load_lds(
      (const __attribute__((address_space(1))) unsigned int*)g,
      (__attribute__((address_space(3))) unsigned int*)l, 16, 0, 0);
}

// ---- bf16 MFMA GEMM: C[M,N] = A[M,K] * B[N,K]^T (m97 recipe + XOR swizzle)
__global__ __launch_bounds__(256) void mgemm(
    const ushort* __restrict__ A, const ushort* __restrict__ B,
    float* __restrict__ C, int M, int N, int K) {
  __shared__ __align__(16) ushort As[128 * 64];
  __shared__ __align__(16) ushort Bs[128 * 64];
  const int tid = threadIdx.x;
  const int lane = tid & 63, w = tid >> 6;
  const int quad = lane >> 4, l16 = lane & 15;
  const int m0 = blockIdx.y * 128, n0 = blockIdx.x * 128;
  const int mq = (w & 1) * 64, nq = (w >> 1) * 64;
  f32x4 acc[4][4];
  const f32x4 fz = {0.f, 0.f, 0.f, 0.f};
  #pragma unroll
  for (int i = 0; i < 4; ++i)
    #pragma unroll
    for (int j = 0; j < 4; ++j) acc[i][j] = fz;

  for (int k0 = 0; k0 < K; k0 += 64) {
    __syncthreads();
    #pragma unroll
    for (int j = 0; j < 4; ++j) {
      int ci = j * 256 + tid;
      int row = ci >> 3, cl = ci & 7;
      int kc = cl ^ (row & 7);
      glds16(A + ((size_t)(m0 + row) * K + k0 + kc * 8), &As[ci * 8]);
      glds16(B + ((size_t)(n0 + row) * K + k0 + kc * 8), &Bs[ci * 8]);
    }
    __syncthreads();
    #pragma unroll
    for (int kt = 0; kt < 2; ++kt) {
      short8_t af[4], bf_[4];
      #pragma unroll
      for (int mt = 0; mt < 4; ++mt) {
        int row = mq + mt * 16 + l16;
        int cl = (kt * 4 + quad) ^ (row & 7);
        af[mt] = *(const short8_t*)&As[row * 64 + cl * 8];
      }
      #pragma unroll
      for (int nt = 0; nt < 4; ++nt) {
        int row = nq + nt * 16 + l16;
        int cl = (kt * 4 + quad) ^ (row & 7);
        bf_[nt] = *(const short8_t*)&Bs[row * 64 + cl * 8];
      }
      #pragma unroll
      for (int mt = 0; mt < 4; ++mt)
        #pragma unroll
        for (int nt = 0; nt < 4; ++nt)
          acc[mt][nt] = __builtin_amdgcn_mfma_f32_16x16x32_bf16(
              af[mt], bf_[nt], acc[mt][nt], 0, 0, 0);
    }
  }
  #pragma unroll
  for (int mt = 0; mt < 4; ++mt)
    #pragma unroll
    for (int nt = 0; nt < 4; ++nt)
      #pragma unroll
      for (int r = 0; r < 4; ++r) {
        int m = m0 + mq + mt * 16 + quad * 4 + r;
        int n = n0 + nq + nt * 16 + l16;
        C[(size_t)m * N + n] = acc[mt][nt][r];
      }
}

// ---------------- conversions / packing ----------------
__global__ __launch_bounds__(256) void cvt_bf(const float* __restrict__ src,
                                              ushort* __restrict__ dst, int n) {
  int i = blockIdx.x * 256 + threadIdx.x;
  if (i < n) dst[i] = f2bf(src[i]);
}

__global__ __launch_bounds__(256) void cvt_sum2_bf(const float* __restrict__ a,
                                                   const float* __restrict__ b,
                                                   ushort* __restrict__ dst, int n) {
  int i = blockIdx.x * 256 + threadIdx.x;
  if (i < n) dst[i] = f2bf(a[i] + b[i]);
}

__global__ __launch_bounds__(256) void pack_wkvg(
    const float* __restrict__ Wk, const float* __restrict__ Wv,
    const float* __restrict__ Wg, ushort* __restrict__ dst) {
  int i = blockIdx.x * 256 + threadIdx.x;
  if (i >= KVGW * 2048) return;
  int n = i >> 11, k = i & 2047;
  float v;
  if (n < 128) v = Wk[(size_t)n * 2048 + k];
  else if (n < 256) v = Wv[(size_t)(n - 128) * 2048 + k];
  else if (n < 259) v = Wg[(size_t)(n - 256) * 2048 + k];
  else v = 0.f;
  dst[i] = f2bf(v);
}

// vt[g][d][s] bf16 from kvg v-part (v is NOT roped)
__global__ __launch_bounds__(256) void cvt_vt(const float* __restrict__ kvg,
                                              ushort* __restrict__ vt) {
  int i = blockIdx.x * 256 + threadIdx.x;
  if (i >= T_SEQ * NG * HD) return;
  int d = i & 63, g = (i >> 6) & 1, s = i >> 7;
  vt[((size_t)g * HD + d) * T_SEQ + s] =
      f2bf(kvg[(size_t)s * KVGW + 128 + g * 64 + d]);
}

// ------- RoPE: q fp32 -> qbf bf16; kvg k-part roped in place + kbf bf16 ----
__global__ __launch_bounds__(256) void rope_all(
    const float* __restrict__ q, float* __restrict__ kvg,
    ushort* __restrict__ qbf, ushort* __restrict__ kbf) {
  const int t = blockIdx.x;
  const float lnb_over = 9.210340371976184f / 32.f;  // ln(10000)/32
  for (int job = threadIdx.x; job < (NHQ + NG) * 32; job += 256) {
    int h = job >> 5, j = job & 31;
    float inv = expf(-(float)j * lnb_over);
    float fr = (float)t * inv;
    float c_ = cosf(fr), s_ = sinf(fr);
    if (h < NHQ) {
      const float* base = q + ((size_t)t * NHQ + h) * HD;
      float x1 = base[j], x2 = base[j + 32];
      ushort* ob = qbf + ((size_t)t * NHQ + h) * HD;
      ob[j] = f2bf(x1 * c_ - x2 * s_);
      ob[j + 32] = f2bf(x2 * c_ + x1 * s_);
    } else {
      int g = h - NHQ;
      float* base = kvg + (size_t)t * KVGW + g * 64;
      float x1 = base[j], x2 = base[j + 32];
      float o1 = x1 * c_ - x2 * s_, o2 = x2 * c_ + x1 * s_;
      base[j] = o1; base[j + 32] = o2;
      kbf[(size_t)t * 128 + g * 64 + j] = f2bf(o1);
      kbf[(size_t)t * 128 + g * 64 + j + 32] = f2bf(o2);
    }
  }
}

// ------- compression: bf16 ck[c][g][d] and transposed bf16 cv^T[g][d][c] ---
// grid (128, 2); c==127 writes the zero pad row (c is padded 127 -> 128).
__global__ __launch_bounds__(256) void compress_kv(
    const float* __restrict__ kvg,
    const float* __restrict__ Wck, const float* __restrict__ Wcv,
    ushort* __restrict__ ck16, ushort* __restrict__ cvt16) {
  const int c = blockIdx.x, g = blockIdx.y;
  const int tid = threadIdx.x;
  if (c == 127) {  // zero pad so MFMA never touches garbage
    if (tid < 64) ck16[((size_t)127 * NG + g) * HD + tid] = 0;
    else if (tid < 128) cvt16[((size_t)g * HD + (tid - 64)) * 128 + 127] = 0;
    return;
  }
  const int d = tid & 63, chunk = tid >> 6;
  __shared__ float red[2][4][64];
  float ak = 0.f, av = 0.f;
  for (int f = chunk * 512; f < chunk * 512 + 512; ++f) {
    int i = f >> 6, e = f & 63;
    int trow = c * CSTRIDE + i;
    float kv = kvg[(size_t)trow * KVGW + g * 64 + e];
    float vv = kvg[(size_t)trow * KVGW + 128 + g * 64 + e];
    ak += kv * Wck[((size_t)g * 2048 + f) * HD + d];
    av += vv * Wcv[((size_t)g * 2048 + f) * HD + d];
  }
  red[0][chunk][d] = ak;
  red[1][chunk][d] = av;
  __syncthreads();
  if (tid < 64) {
    ck16[((size_t)c * NG + g) * HD + tid] =
        f2bf(red[0][0][tid] + red[0][1][tid] + red[0][2][tid] + red[0][3][tid]);
  } else if (tid < 128) {
    int dd = tid - 64;
    cvt16[((size_t)g * HD + dd) * 128 + c] =
        f2bf(red[1][0][dd] + red[1][1][dd] + red[1][2][dd] + red[1][3][dd]);
  }
}

// ------- MFMA compressed attention + block scores + parallel top-16 -------
// grid (128 t-tiles of 16, 2 g), 512 threads = 8 waves x 2 heads each.
__global__ __launch_bounds__(512) void comp_attn(
    const ushort* __restrict__ qbf, const ushort* __restrict__ ck16,
    const ushort* __restrict__ cvt16, const float* __restrict__ kvg,
    float* __restrict__ comb, unsigned* __restrict__ sel) {
  const int tb = blockIdx.x, g = blockIdx.y;
  const int t0 = tb * 16;
  const int tid = threadIdx.x, lane = tid & 63, w = tid >> 6;
  const int quad = lane >> 4, l16 = lane & 15;
  const int qb = t0 >> 6;  // uniform across the 16 t's of this block

  __shared__ float colsum[16][129];  // [t_local][c], padded vs bank conflicts
  for (int i = tid; i < 16 * 129; i += 512) ((float*)colsum)[i] = 0.f;
  __syncthreads();

  const int t = t0 + l16;
  const int cmaxv = (t >= 31) ? min(126, (t - 31) >> 4) : -1;
  const int h0 = w * 2;  // two heads per wave

  short8_t qB[2][2];
  #pragma unroll
  for (int hh = 0; hh < 2; ++hh)
    #pragma unroll
    for (int kd = 0; kd < 2; ++kd)
      qB[hh][kd] = *(const short8_t*)(qbf +
          ((size_t)t * NHQ + g * 16 + h0 + hh) * HD + kd * 32 + quad * 8);

  const f32x4 fz = {0.f, 0.f, 0.f, 0.f};
  f32x4 sp[2][8];

  #pragma unroll
  for (int ct = 0; ct < 8; ++ct) {
    const ushort* kr = ck16 + ((size_t)(ct * 16 + l16) * NG + g) * HD + quad * 8;
    short8_t kA0 = *(const short8_t*)kr;
    short8_t kA1 = *(const short8_t*)(kr + 32);
    #pragma unroll
    for (int hh = 0; hh < 2; ++hh) {
      f32x4 c0 = __builtin_amdgcn_mfma_f32_16x16x32_bf16(kA0, qB[hh][0], fz, 0, 0, 0);
      sp[hh][ct] = __builtin_amdgcn_mfma_f32_16x16x32_bf16(kA1, qB[hh][1], c0, 0, 0, 0);
    }
  }

  short4_t pB[2][8];
  #pragma unroll
  for (int hh = 0; hh < 2; ++hh) {
    float mx = -INFINITY;
    #pragma unroll
    for (int ct = 0; ct < 8; ++ct)
      #pragma unroll
      for (int r = 0; r < 4; ++r) {
        int c = ct * 16 + quad * 4 + r;
        float s_ = (c <= cmaxv) ? sp[hh][ct][r] * SCALE : -INFINITY;
        sp[hh][ct][r] = s_;
        mx = fmaxf(mx, s_);
      }
    mx = fmaxf(mx, __shfl_xor(mx, 16));
    mx = fmaxf(mx, __shfl_xor(mx, 32));
    if (mx == -INFINITY) mx = 0.f;  // fully-masked rows (t < 31)
    float ls = 0.f;
    #pragma unroll
    for (int ct = 0; ct < 8; ++ct)
      #pragma unroll
      for (int r = 0; r < 4; ++r) {
        float p = __expf(sp[hh][ct][r] - mx);
        sp[hh][ct][r] = p;
        ls += p;
      }
    ls += __shfl_xor(ls, 16);
    ls += __shfl_xor(ls, 32);
    float inv = (ls > 0.f) ? 1.f / ls : 0.f;
    #pragma unroll
    for (int ct = 0; ct < 8; ++ct) {
      short4_t pk;
      #pragma unroll
      for (int r = 0; r < 4; ++r) {
        float pn = sp[hh][ct][r] * inv;
        sp[hh][ct][r] = pn;
        pk[r] = (short)f2bf(pn);
      }
      pB[hh][ct] = pk;
    }
  }

  #pragma unroll
  for (int ct = 0; ct < 8; ++ct)
    #pragma unroll
    for (int r = 0; r < 4; ++r)
      atomicAdd(&colsum[l16][ct * 16 + quad * 4 + r],
                sp[0][ct][r] + sp[1][ct][r]);

  f32x4 acc[2][4];
  #pragma unroll
  for (int hh = 0; hh < 2; ++hh)
    #pragma unroll
    for (int dt = 0; dt < 4; ++dt) acc[hh][dt] = fz;
  #pragma unroll
  for (int ct = 0; ct < 8; ++ct) {
    short4_t vA[4];
    #pragma unroll
    for (int dt = 0; dt < 4; ++dt)
      vA[dt] = *(const short4_t*)(cvt16 +
          ((size_t)g * HD + dt * 16 + l16) * 128 + ct * 16 + quad * 4);
    #pragma unroll
    for (int hh = 0; hh < 2; ++hh)
      #pragma unroll
      for (int dt = 0; dt < 4; ++dt)
        acc[hh][dt] = __builtin_amdgcn_mfma_f32_16x16x16bf16_1k(
            vA[dt], pB[hh][ct], acc[hh][dt], 0, 0, 0);
  }

  const float g0 = 1.f / (1.f + __expf(-kvg[(size_t)t * KVGW + 256]));
  #pragma unroll
  for (int hh = 0; hh < 2; ++hh)
    #pragma unroll
    for (int dt = 0; dt < 4; ++dt)
      #pragma unroll
      for (int r = 0; r < 4; ++r)
        comb[((size_t)t * NHQ + g * 16 + h0 + hh) * HD + dt * 16 + quad * 4 + r] =
            g0 * acc[hh][dt][r];

  __syncthreads();

  {
    const int tl = tid >> 5;   // 0..15
    const int b = tid & 31;
    float s;
    if (b > qb) s = -INFINITY;
    else if (b == 0 || qb - b < 2) s = INFINITY;
    else {
      s = 0.f;
      #pragma unroll
      for (int i = 0; i < 5; ++i) s += colsum[tl][4 * b - 1 + i];
    }
    unsigned key = (s < 0.f) ? 0u : (__float_as_uint(s) + 1u);
    unsigned msel = 0;
    for (int it = 0; it < 16; ++it) {
      unsigned long long pk =
          (((unsigned long long)key) << 6) | (unsigned)(63 - b);
      #pragma unroll
      for (int off = 16; off >= 1; off >>= 1) {
        unsigned long long o = __shfl_xor(pk, off);
        if (o > pk) pk = o;
      }
      if ((pk >> 6) == 0) break;  // uniform within the 32-group
      int bs = 63 - (int)(pk & 63);
      msel |= 1u << bs;
      if (b == bs) key = 0;
    }
    if (b == 0) sel[(size_t)(t0 + tl) * NG + g] = msel;
  }
}

// ------- MFMA flash attention, 256 thr = 4 waves = 1 head x 4-way list
// split (fine-grain for tail balance). grid (32 qb, 2 g, 32 = 16 hg x 2 mode).
// Cheap masks: only diag block needs causal, only qb-8 (mode1) needs window;
// mode0 selection bit is uniform over a qt's 16 keys. Defer-max (T13, THR=8)
// skips the acc rescale almost always. setprio(1) around MFMA clusters (T5).
// (256,4): 4 blocks/CU -> 16 waves/CU -> 128-VGPR cap (same budget that fit
// 124 VGPR with no spill in the 512-thread version).
__global__ __launch_bounds__(256, 4) void mfma_attn(
    const ushort* __restrict__ qb16, const ushort* __restrict__ kb16,
    const ushort* __restrict__ vtb, const float* __restrict__ kvg,
    const unsigned* __restrict__ sel, float* __restrict__ comb1,
    float* __restrict__ comb2) {
  const int qb = blockIdx.x, g = blockIdx.y;
  const int hg = blockIdx.z & 15, mode = blockIdx.z >> 4;
  const int tid = threadIdx.x, lane = tid & 63, w = tid >> 6;  // 4 waves
  const int quad = lane >> 4, l16 = lane & 15;
  const int head = g * 16 + hg;
  const int split = w;  // quarter of the key-block list
  const int t0 = qb * 64;

  __shared__ unsigned sel_s[64];
  __shared__ float pml[3][2][4][64];      // [w-1][m|l][qt][lane]  6 KB
  __shared__ short4_t pacc[3][4][4][64];  // [w-1][dt][qt][lane]  24 KB

  if (tid < 64) sel_s[tid] = sel[(size_t)(t0 + tid) * NG + g];
  __syncthreads();

  short8_t qB[4][2];
  #pragma unroll
  for (int qt = 0; qt < 4; ++qt)
    #pragma unroll
    for (int kd = 0; kd < 2; ++kd)
      qB[qt][kd] = *(const short8_t*)(qb16 +
          ((size_t)(t0 + qt * 16 + l16) * NHQ + head) * HD + kd * 32 + quad * 8);

  unsigned sbq[4];
  #pragma unroll
  for (int qt = 0; qt < 4; ++qt) sbq[qt] = sel_s[qt * 16 + l16];

  float m_[4], l_[4];
  f32x4 acc[4][4];
  const f32x4 fz = {0.f, 0.f, 0.f, 0.f};
  #pragma unroll
  for (int qt = 0; qt < 4; ++qt) { m_[qt] = -1e30f; l_[qt] = 0.f; }
  #pragma unroll
  for (int dt = 0; dt < 4; ++dt)
    #pragma unroll
    for (int qt = 0; qt < 4; ++qt) acc[dt][qt] = fz;

  // my quarter of the block list (interleaved for balance)
  unsigned mrem = 0; int b0 = 0, nb = 0;
  if (mode == 0) {
    unsigned uni = sel_s[lane];  // wave-parallel union OR-reduce
    #pragma unroll
    for (int off = 32; off >= 1; off >>= 1) uni |= __shfl_xor(uni, off);
    int cnt = 0;
    while (uni) {
      int b = __ffs(uni) - 1; uni &= uni - 1;
      if ((cnt++ & 3) == split) mrem |= 1u << b;
    }
    nb = __popc(mrem);
  } else {
    b0 = ((qb > 8) ? qb - 8 : 0) + split;
    nb = (qb >= b0) ? (qb - b0) / 4 + 1 : 0;
  }

  for (int ib = 0; ib < nb; ++ib) {
    int blk;
    if (mode == 0) { blk = __ffs(mrem) - 1; mrem &= mrem - 1; } else { blk = b0 + 4 * ib; }

    // S^T = K Q^T
    f32x4 sp[4][4];
    __builtin_amdgcn_s_setprio(1);
    #pragma unroll
    for (int kt = 0; kt < 4; ++kt) {
      const ushort* kr = kb16 + (size_t)(blk * 64 + kt * 16 + l16) * 128 + g * 64 + quad * 8;
      short8_t kA0 = *(const short8_t*)kr;
      short8_t kA1 = *(const short8_t*)(kr + 32);
      #pragma unroll
      for (int qt = 0; qt < 4; ++qt) {
        f32x4 c = __builtin_amdgcn_mfma_f32_16x16x32_bf16(kA0, qB[qt][0], fz, 0, 0, 0);
        sp[kt][qt] = __builtin_amdgcn_mfma_f32_16x16x32_bf16(kA1, qB[qt][1], c, 0, 0, 0);
      }
    }
    __builtin_amdgcn_s_setprio(0);

    const bool diag = (blk == qb);                     // causal mask needed
    const bool wedge = (mode == 1) && (blk == qb - 8); // window-edge mask

    short4_t pB[4][4];
    #pragma unroll
    for (int qt = 0; qt < 4; ++qt) {
      const int qg = t0 + qt * 16 + l16;
      const bool selq = (mode != 0) || (((sbq[qt] >> blk) & 1u) != 0);
      float mx = -INFINITY;
      if (!diag && !wedge) {
        // whole 64-key block valid iff selq (uniform across the 16 keys)
        const float scl = selq ? SCALE : 0.f;
        const float bia = selq ? 0.f : -INFINITY;
        #pragma unroll
        for (int kt = 0; kt < 4; ++kt)
          #pragma unroll
          for (int r = 0; r < 4; ++r) {
            float s_ = sp[kt][qt][r] * scl + bia;
            sp[kt][qt][r] = s_;
            mx = fmaxf(mx, s_);
          }
      } else {
        #pragma unroll
        for (int kt = 0; kt < 4; ++kt)
          #pragma unroll
          for (int r = 0; r < 4; ++r) {
            int key = blk * 64 + kt * 16 + quad * 4 + r;
            bool ok = selq && (key <= qg) && (qg - key <= 512);
            float s_ = ok ? sp[kt][qt][r] * SCALE : -INFINITY;
            sp[kt][qt][r] = s_;
            mx = fmaxf(mx, s_);
          }
      }
      mx = fmaxf(mx, __shfl_xor(mx, 16));
      mx = fmaxf(mx, __shfl_xor(mx, 32));
      float mold = m_[qt];
      if (!__all(mx <= mold + 8.f)) {  // T13 defer-max: rescale rarely
        float mnew = fmaxf(mold, mx);
        float alpha = __expf(mold - mnew);
        l_[qt] *= alpha;
        #pragma unroll
        for (int dt = 0; dt < 4; ++dt)
          #pragma unroll
          for (int r = 0; r < 4; ++r) acc[dt][qt][r] *= alpha;
        m_[qt] = mnew;
        mold = mnew;
      }
      float ps = 0.f;
      #pragma unroll
      for (int kt = 0; kt < 4; ++kt) {
        short4_t pb;
        #pragma unroll
        for (int r = 0; r < 4; ++r) {
          float p = __expf(sp[kt][qt][r] - mold);  // exp(-inf)=0; p <= e^8
          ps += p;
          pb[r] = pbf(p);
        }
        pB[kt][qt] = pb;
      }
      ps += __shfl_xor(ps, 16);
      ps += __shfl_xor(ps, 32);
      l_[qt] += ps;
    }

    // O^T += V^T P^T
    __builtin_amdgcn_s_setprio(1);
    #pragma unroll
    for (int kt = 0; kt < 4; ++kt) {
      short4_t vA[4];
      #pragma unroll
      for (int dt = 0; dt < 4; ++dt)
        vA[dt] = *(const short4_t*)(vtb +
            ((size_t)g * HD + dt * 16 + l16) * T_SEQ + blk * 64 + kt * 16 + quad * 4);
      #pragma unroll
      for (int dt = 0; dt < 4; ++dt)
        #pragma unroll
        for (int qt = 0; qt < 4; ++qt)
          acc[dt][qt] = __builtin_amdgcn_mfma_f32_16x16x16bf16_1k(
              vA[dt], pB[kt][qt], acc[dt][qt], 0, 0, 0);
    }
    __builtin_amdgcn_s_setprio(0);
  }

  // publish partials from waves 1..3, merge + epilogue in wave 0
  if (w > 0) {
    const int ws = w - 1;
    #pragma unroll
    for (int qt = 0; qt < 4; ++qt) {
      pml[ws][0][qt][lane] = m_[qt];
      pml[ws][1][qt][lane] = l_[qt];
    }
    #pragma unroll
    for (int dt = 0; dt < 4; ++dt)
      #pragma unroll
      for (int qt = 0; qt < 4; ++qt) {
        short4_t pk;
        #pragma unroll
        for (int r = 0; r < 4; ++r) pk[r] = (short)f2bf(acc[dt][qt][r]);
        pacc[ws][dt][qt][lane] = pk;
      }
  }
  __syncthreads();
  if (w == 0) {
    for (int s2 = 0; s2 < 3; ++s2) {
      float a1[4], a2[4];
      #pragma unroll
      for (int qt = 0; qt < 4; ++qt) {
        float m2 = pml[s2][0][qt][lane], l2 = pml[s2][1][qt][lane];
        float mN = fmaxf(m_[qt], m2);
        a1[qt] = __expf(m_[qt] - mN);
        a2[qt] = __expf(m2 - mN);
        l_[qt] = l_[qt] * a1[qt] + l2 * a2[qt];
        m_[qt] = mN;
      }
      #pragma unroll
      for (int dt = 0; dt < 4; ++dt)
        #pragma unroll
        for (int qt = 0; qt < 4; ++qt) {
          short4_t pk = pacc[s2][dt][qt][lane];
          #pragma unroll
          for (int r = 0; r < 4; ++r)
            acc[dt][qt][r] = acc[dt][qt][r] * a1[qt] + bf2f((ushort)pk[r]) * a2[qt];
        }
    }
    // epilogue
    #pragma unroll
    for (int qt = 0; qt < 4; ++qt) {
      const int t = t0 + qt * 16 + l16;
      const float c_ =
          (1.f / (1.f + __expf(-kvg[(size_t)t * KVGW + 257 + mode]))) / l_[qt];
      #pragma unroll
      for (int dt = 0; dt < 4; ++dt)
        #pragma unroll
        for (int r = 0; r < 4; ++r) {
          const int d = dt * 16 + quad * 4 + r;
          size_t idx = ((size_t)t * NHQ + head) * HD + d;
          if (mode == 0) comb1[idx] += c_ * acc[dt][qt][r];
          else           comb2[idx]  = c_ * acc[dt][qt][r];
        }
    }
  }
}

extern "C" void kernel_launch(void* const* d_in, const int* in_sizes, int n_in,
                              void* d_out, int out_size, void* d_ws, size_t ws_size,
                              hipStream_t stream) {
  const float* x   = (const float*)d_in[0];
  const float* Wq  = (const float*)d_in[1];
  const float* Wk  = (const float*)d_in[2];
  const float* Wv  = (const float*)d_in[3];
  const float* Wo  = (const float*)d_in[4];
  const float* Wg  = (const float*)d_in[5];
  const float* Wck = (const float*)d_in[6];
  const float* Wcv = (const float*)d_in[7];
  float* out = (float*)d_out;
  float* ws = (float*)d_ws;

  float* qbuf   = ws;                           // 4,194,304 f
  float* comb1  = qbuf + 4194304;               // 4,194,304 f
  float* kvg    = comb1 + 4194304;              //   786,432 f
  float* ckb    = kvg + 786432;                 //    16,384 f (bf16 ck+cvT)
  float* cvb    = ckb + 16384;                  //    16,384 f (unused)
  unsigned* sel = (unsigned*)(cvb + 16384);     //     4,096 u32
  ushort* kbf   = (ushort*)(sel + 4096);        //   262,144 u16
  ushort* vtb   = kbf + 262144;                 //   262,144 u16
  ushort* wkvgb = vtb + 262144;                 //   786,432 u16
  ushort* regA  = wkvgb + 786432;               // 4,194,304 u16: xb -> combb
  ushort* regB  = regA + 4194304;               // 4,194,304 u16: wqb -> qbf
  ushort* xb = regA;      ushort* combb = regA;
  ushort* wqb = regB;     ushort* qbf = regB;
  float* comb2 = qbuf;                // fp32 q dead after rope_all
  ushort* wob = (ushort*)qbuf;        // written after comb2 consumed

  ushort* ckb16 = (ushort*)ckb;       // 128*2*64 u16 = 32 KB
  ushort* cvtb  = ckb16 + 16384;      // 2*64*128 u16 = 32 KB (within ckb slot)

  const int CV = (4194304 + 255) / 256;
  cvt_bf<<<CV, 256, 0, stream>>>(x, xb, 4194304);
  cvt_bf<<<CV, 256, 0, stream>>>(Wq, wqb, 4194304);
  pack_wkvg<<<(KVGW * 2048 + 255) / 256, 256, 0, stream>>>(Wk, Wv, Wg, wkvgb);

  mgemm<<<dim3(16, 16), 256, 0, stream>>>(xb, wqb, qbuf, 2048, 2048, 2048);
  mgemm<<<dim3(3, 16), 256, 0, stream>>>(xb, wkvgb, kvg, 2048, KVGW, 2048);

  rope_all<<<2048, 256, 0, stream>>>(qbuf, kvg, qbf, kbf);
  cvt_vt<<<(262144 + 255) / 256, 256, 0, stream>>>(kvg, vtb);
  compress_kv<<<dim3(128, 2), 256, 0, stream>>>(kvg, Wck, Wcv, ckb16, cvtb);
  comp_attn<<<dim3(128, 2), 512, 0, stream>>>(qbf, ckb16, cvtb, kvg, comb1, sel);
  mfma_attn<<<dim3(32, 2, 32), 256, 0, stream>>>(qbf, kbf, vtb, kvg, sel, comb1, comb2);

  cvt_sum2_bf<<<CV, 256, 0, stream>>>(comb1, comb2, combb, 4194304);
  cvt_bf<<<CV, 256, 0, stream>>>(Wo, wob, 4194304);
  mgemm<<<dim3(16, 16), 256, 0, stream>>>(combb, wob, out, 2048, 2048, 2048);
}

// Round 4
// 495.177 us; speedup vs baseline: 1.6271x; 1.6271x over previous
//
#include <hip/hip_runtime.h>
#include <math.h>

#define T_SEQ 2048
#define NHQ 32
#define NG 2
#define HD 64
#define CSTRIDE 16
#define SCALE 0.125f
#define KVGW 384  // fused k|v|gate row width: 128 k + 128 v + 3 gate + pad

typedef __attribute__((ext_vector_type(8))) short short8_t;
typedef __attribute__((ext_vector_type(4))) short short4_t;
typedef __attribute__((ext_vector_type(4))) float f32x4;

__device__ __forceinline__ ushort f2bf(float x) {  // round-to-nearest-even
  union { float f; unsigned u; } c; c.f = x;
  unsigned r = c.u + 0x7fff + ((c.u >> 16) & 1);
  return (ushort)(r >> 16);
}
__device__ __forceinline__ short pbf(float x) {  // cheap round-half-up (x>=0)
  union { float f; unsigned u; } c; c.f = x;
  return (short)((c.u + 0x8000u) >> 16);
}
__device__ __forceinline__ float bf2f(ushort u) {
  union { unsigned u; float f; } c; c.u = ((unsigned)u) << 16;
  return c.f;
}

__device__ __forceinline__ void glds16(const ushort* g, ushort* l) {
  __builtin_amdgcn_global_load_lds(
      (const __attribute__((address_space(1))) unsigned int*)g,
      (__attribute__((address_space(3))) unsigned int*)l, 16, 0, 0);
}

// ---- bf16 MFMA GEMM: C[M,N] = A[M,K] * B[N,K]^T (m97 recipe + XOR swizzle)
__global__ __launch_bounds__(256) void mgemm(
    const ushort* __restrict__ A, const ushort* __restrict__ B,
    float* __restrict__ C, int M, int N, int K) {
  __shared__ __align__(16) ushort As[128 * 64];
  __shared__ __align__(16) ushort Bs[128 * 64];
  const int tid = threadIdx.x;
  const int lane = tid & 63, w = tid >> 6;
  const int quad = lane >> 4, l16 = lane & 15;
  const int m0 = blockIdx.y * 128, n0 = blockIdx.x * 128;
  const int mq = (w & 1) * 64, nq = (w >> 1) * 64;
  f32x4 acc[4][4];
  const f32x4 fz = {0.f, 0.f, 0.f, 0.f};
  #pragma unroll
  for (int i = 0; i < 4; ++i)
    #pragma unroll
    for (int j = 0; j < 4; ++j) acc[i][j] = fz;

  for (int k0 = 0; k0 < K; k0 += 64) {
    __syncthreads();
    #pragma unroll
    for (int j = 0; j < 4; ++j) {
      int ci = j * 256 + tid;
      int row = ci >> 3, cl = ci & 7;
      int kc = cl ^ (row & 7);
      glds16(A + ((size_t)(m0 + row) * K + k0 + kc * 8), &As[ci * 8]);
      glds16(B + ((size_t)(n0 + row) * K + k0 + kc * 8), &Bs[ci * 8]);
    }
    __syncthreads();
    #pragma unroll
    for (int kt = 0; kt < 2; ++kt) {
      short8_t af[4], bf_[4];
      #pragma unroll
      for (int mt = 0; mt < 4; ++mt) {
        int row = mq + mt * 16 + l16;
        int cl = (kt * 4 + quad) ^ (row & 7);
        af[mt] = *(const short8_t*)&As[row * 64 + cl * 8];
      }
      #pragma unroll
      for (int nt = 0; nt < 4; ++nt) {
        int row = nq + nt * 16 + l16;
        int cl = (kt * 4 + quad) ^ (row & 7);
        bf_[nt] = *(const short8_t*)&Bs[row * 64 + cl * 8];
      }
      #pragma unroll
      for (int mt = 0; mt < 4; ++mt)
        #pragma unroll
        for (int nt = 0; nt < 4; ++nt)
          acc[mt][nt] = __builtin_amdgcn_mfma_f32_16x16x32_bf16(
              af[mt], bf_[nt], acc[mt][nt], 0, 0, 0);
    }
  }
  #pragma unroll
  for (int mt = 0; mt < 4; ++mt)
    #pragma unroll
    for (int nt = 0; nt < 4; ++nt)
      #pragma unroll
      for (int r = 0; r < 4; ++r) {
        int m = m0 + mq + mt * 16 + quad * 4 + r;
        int n = n0 + nq + nt * 16 + l16;
        C[(size_t)m * N + n] = acc[mt][nt][r];
      }
}

// ---------------- conversions / packing ----------------
__global__ __launch_bounds__(256) void cvt_bf(const float* __restrict__ src,
                                              ushort* __restrict__ dst, int n) {
  int i = blockIdx.x * 256 + threadIdx.x;
  if (i < n) dst[i] = f2bf(src[i]);
}

__global__ __launch_bounds__(256) void cvt_sum2_bf(const float* __restrict__ a,
                                                   const float* __restrict__ b,
                                                   ushort* __restrict__ dst, int n) {
  int i = blockIdx.x * 256 + threadIdx.x;
  if (i < n) dst[i] = f2bf(a[i] + b[i]);
}

__global__ __launch_bounds__(256) void pack_wkvg(
    const float* __restrict__ Wk, const float* __restrict__ Wv,
    const float* __restrict__ Wg, ushort* __restrict__ dst) {
  int i = blockIdx.x * 256 + threadIdx.x;
  if (i >= KVGW * 2048) return;
  int n = i >> 11, k = i & 2047;
  float v;
  if (n < 128) v = Wk[(size_t)n * 2048 + k];
  else if (n < 256) v = Wv[(size_t)(n - 128) * 2048 + k];
  else if (n < 259) v = Wg[(size_t)(n - 256) * 2048 + k];
  else v = 0.f;
  dst[i] = f2bf(v);
}

// vt[g][d][s] bf16 from kvg v-part (v is NOT roped)
__global__ __launch_bounds__(256) void cvt_vt(const float* __restrict__ kvg,
                                              ushort* __restrict__ vt) {
  int i = blockIdx.x * 256 + threadIdx.x;
  if (i >= T_SEQ * NG * HD) return;
  int d = i & 63, g = (i >> 6) & 1, s = i >> 7;
  vt[((size_t)g * HD + d) * T_SEQ + s] =
      f2bf(kvg[(size_t)s * KVGW + 128 + g * 64 + d]);
}

// ------- RoPE: q fp32 -> qbf bf16; kvg k-part roped in place + kbf bf16 ----
__global__ __launch_bounds__(256) void rope_all(
    const float* __restrict__ q, float* __restrict__ kvg,
    ushort* __restrict__ qbf, ushort* __restrict__ kbf) {
  const int t = blockIdx.x;
  const float lnb_over = 9.210340371976184f / 32.f;  // ln(10000)/32
  for (int job = threadIdx.x; job < (NHQ + NG) * 32; job += 256) {
    int h = job >> 5, j = job & 31;
    float inv = expf(-(float)j * lnb_over);
    float fr = (float)t * inv;
    float c_ = cosf(fr), s_ = sinf(fr);
    if (h < NHQ) {
      const float* base = q + ((size_t)t * NHQ + h) * HD;
      float x1 = base[j], x2 = base[j + 32];
      ushort* ob = qbf + ((size_t)t * NHQ + h) * HD;
      ob[j] = f2bf(x1 * c_ - x2 * s_);
      ob[j + 32] = f2bf(x2 * c_ + x1 * s_);
    } else {
      int g = h - NHQ;
      float* base = kvg + (size_t)t * KVGW + g * 64;
      float x1 = base[j], x2 = base[j + 32];
      float o1 = x1 * c_ - x2 * s_, o2 = x2 * c_ + x1 * s_;
      base[j] = o1; base[j + 32] = o2;
      kbf[(size_t)t * 128 + g * 64 + j] = f2bf(o1);
      kbf[(size_t)t * 128 + g * 64 + j + 32] = f2bf(o2);
    }
  }
}

// ------- compression: bf16 ck[c][g][d] and transposed bf16 cv^T[g][d][c] ---
// grid (128, 2); c==127 writes the zero pad row (c is padded 127 -> 128).
__global__ __launch_bounds__(256) void compress_kv(
    const float* __restrict__ kvg,
    const float* __restrict__ Wck, const float* __restrict__ Wcv,
    ushort* __restrict__ ck16, ushort* __restrict__ cvt16) {
  const int c = blockIdx.x, g = blockIdx.y;
  const int tid = threadIdx.x;
  if (c == 127) {  // zero pad so MFMA never touches garbage
    if (tid < 64) ck16[((size_t)127 * NG + g) * HD + tid] = 0;
    else if (tid < 128) cvt16[((size_t)g * HD + (tid - 64)) * 128 + 127] = 0;
    return;
  }
  const int d = tid & 63, chunk = tid >> 6;
  __shared__ float red[2][4][64];
  float ak = 0.f, av = 0.f;
  for (int f = chunk * 512; f < chunk * 512 + 512; ++f) {
    int i = f >> 6, e = f & 63;
    int trow = c * CSTRIDE + i;
    float kv = kvg[(size_t)trow * KVGW + g * 64 + e];
    float vv = kvg[(size_t)trow * KVGW + 128 + g * 64 + e];
    ak += kv * Wck[((size_t)g * 2048 + f) * HD + d];
    av += vv * Wcv[((size_t)g * 2048 + f) * HD + d];
  }
  red[0][chunk][d] = ak;
  red[1][chunk][d] = av;
  __syncthreads();
  if (tid < 64) {
    ck16[((size_t)c * NG + g) * HD + tid] =
        f2bf(red[0][0][tid] + red[0][1][tid] + red[0][2][tid] + red[0][3][tid]);
  } else if (tid < 128) {
    int dd = tid - 64;
    cvt16[((size_t)g * HD + dd) * 128 + c] =
        f2bf(red[1][0][dd] + red[1][1][dd] + red[1][2][dd] + red[1][3][dd]);
  }
}

// ------- MFMA compressed attention + block scores + parallel top-16 -------
// grid (128 t-tiles of 16, 2 g), 512 threads = 8 waves x 2 heads each.
__global__ __launch_bounds__(512) void comp_attn(
    const ushort* __restrict__ qbf, const ushort* __restrict__ ck16,
    const ushort* __restrict__ cvt16, const float* __restrict__ kvg,
    float* __restrict__ comb, unsigned* __restrict__ sel) {
  const int tb = blockIdx.x, g = blockIdx.y;
  const int t0 = tb * 16;
  const int tid = threadIdx.x, lane = tid & 63, w = tid >> 6;
  const int quad = lane >> 4, l16 = lane & 15;
  const int qb = t0 >> 6;  // uniform across the 16 t's of this block

  __shared__ float colsum[16][129];  // [t_local][c], padded vs bank conflicts
  for (int i = tid; i < 16 * 129; i += 512) ((float*)colsum)[i] = 0.f;
  __syncthreads();

  const int t = t0 + l16;
  const int cmaxv = (t >= 31) ? min(126, (t - 31) >> 4) : -1;
  const int h0 = w * 2;  // two heads per wave

  short8_t qB[2][2];
  #pragma unroll
  for (int hh = 0; hh < 2; ++hh)
    #pragma unroll
    for (int kd = 0; kd < 2; ++kd)
      qB[hh][kd] = *(const short8_t*)(qbf +
          ((size_t)t * NHQ + g * 16 + h0 + hh) * HD + kd * 32 + quad * 8);

  const f32x4 fz = {0.f, 0.f, 0.f, 0.f};
  f32x4 sp[2][8];

  #pragma unroll
  for (int ct = 0; ct < 8; ++ct) {
    const ushort* kr = ck16 + ((size_t)(ct * 16 + l16) * NG + g) * HD + quad * 8;
    short8_t kA0 = *(const short8_t*)kr;
    short8_t kA1 = *(const short8_t*)(kr + 32);
    #pragma unroll
    for (int hh = 0; hh < 2; ++hh) {
      f32x4 c0 = __builtin_amdgcn_mfma_f32_16x16x32_bf16(kA0, qB[hh][0], fz, 0, 0, 0);
      sp[hh][ct] = __builtin_amdgcn_mfma_f32_16x16x32_bf16(kA1, qB[hh][1], c0, 0, 0, 0);
    }
  }

  short4_t pB[2][8];
  #pragma unroll
  for (int hh = 0; hh < 2; ++hh) {
    float mx = -INFINITY;
    #pragma unroll
    for (int ct = 0; ct < 8; ++ct)
      #pragma unroll
      for (int r = 0; r < 4; ++r) {
        int c = ct * 16 + quad * 4 + r;
        float s_ = (c <= cmaxv) ? sp[hh][ct][r] * SCALE : -INFINITY;
        sp[hh][ct][r] = s_;
        mx = fmaxf(mx, s_);
      }
    mx = fmaxf(mx, __shfl_xor(mx, 16));
    mx = fmaxf(mx, __shfl_xor(mx, 32));
    if (mx == -INFINITY) mx = 0.f;  // fully-masked rows (t < 31)
    float ls = 0.f;
    #pragma unroll
    for (int ct = 0; ct < 8; ++ct)
      #pragma unroll
      for (int r = 0; r < 4; ++r) {
        float p = __expf(sp[hh][ct][r] - mx);
        sp[hh][ct][r] = p;
        ls += p;
      }
    ls += __shfl_xor(ls, 16);
    ls += __shfl_xor(ls, 32);
    float inv = (ls > 0.f) ? 1.f / ls : 0.f;
    #pragma unroll
    for (int ct = 0; ct < 8; ++ct) {
      short4_t pk;
      #pragma unroll
      for (int r = 0; r < 4; ++r) {
        float pn = sp[hh][ct][r] * inv;
        sp[hh][ct][r] = pn;
        pk[r] = (short)f2bf(pn);
      }
      pB[hh][ct] = pk;
    }
  }

  #pragma unroll
  for (int ct = 0; ct < 8; ++ct)
    #pragma unroll
    for (int r = 0; r < 4; ++r)
      atomicAdd(&colsum[l16][ct * 16 + quad * 4 + r],
                sp[0][ct][r] + sp[1][ct][r]);

  f32x4 acc[2][4];
  #pragma unroll
  for (int hh = 0; hh < 2; ++hh)
    #pragma unroll
    for (int dt = 0; dt < 4; ++dt) acc[hh][dt] = fz;
  #pragma unroll
  for (int ct = 0; ct < 8; ++ct) {
    short4_t vA[4];
    #pragma unroll
    for (int dt = 0; dt < 4; ++dt)
      vA[dt] = *(const short4_t*)(cvt16 +
          ((size_t)g * HD + dt * 16 + l16) * 128 + ct * 16 + quad * 4);
    #pragma unroll
    for (int hh = 0; hh < 2; ++hh)
      #pragma unroll
      for (int dt = 0; dt < 4; ++dt)
        acc[hh][dt] = __builtin_amdgcn_mfma_f32_16x16x16bf16_1k(
            vA[dt], pB[hh][ct], acc[hh][dt], 0, 0, 0);
  }

  const float g0 = 1.f / (1.f + __expf(-kvg[(size_t)t * KVGW + 256]));
  #pragma unroll
  for (int hh = 0; hh < 2; ++hh)
    #pragma unroll
    for (int dt = 0; dt < 4; ++dt)
      #pragma unroll
      for (int r = 0; r < 4; ++r)
        comb[((size_t)t * NHQ + g * 16 + h0 + hh) * HD + dt * 16 + quad * 4 + r] =
            g0 * acc[hh][dt][r];

  __syncthreads();

  {
    const int tl = tid >> 5;   // 0..15
    const int b = tid & 31;
    float s;
    if (b > qb) s = -INFINITY;
    else if (b == 0 || qb - b < 2) s = INFINITY;
    else {
      s = 0.f;
      #pragma unroll
      for (int i = 0; i < 5; ++i) s += colsum[tl][4 * b - 1 + i];
    }
    unsigned key = (s < 0.f) ? 0u : (__float_as_uint(s) + 1u);
    unsigned msel = 0;
    for (int it = 0; it < 16; ++it) {
      unsigned long long pk =
          (((unsigned long long)key) << 6) | (unsigned)(63 - b);
      #pragma unroll
      for (int off = 16; off >= 1; off >>= 1) {
        unsigned long long o = __shfl_xor(pk, off);
        if (o > pk) pk = o;
      }
      if ((pk >> 6) == 0) break;  // uniform within the 32-group
      int bs = 63 - (int)(pk & 63);
      msel |= 1u << bs;
      if (b == bs) key = 0;
    }
    if (b == 0) sel[(size_t)(t0 + tl) * NG + g] = msel;
  }
}

// ------- MFMA flash attention, 256 thr = 4 waves = 1 head x 4-way list
// split (fine-grain for tail balance). grid (32 qb, 2 g, 32 = 16 hg x 2 mode).
// Cheap masks: only diag block needs causal, only qb-8 (mode1) needs window;
// mode0 selection bit is uniform over a qt's 16 keys. Defer-max (T13, THR=8)
// skips the acc rescale almost always. setprio(1) around MFMA clusters (T5).
// LAUNCH BOUNDS: empirically this compiler's VGPR cap = 512/(2*arg2):
// (512,2)->120 VGPR ok; (512,4) and (256,4)->64 VGPR cap, ~1GB scratch
// spill (round-3: FETCH 554MB WRITE 932MB, 470us). (256,2) -> 128 cap,
// fits ~124 VGPR, HW still co-resides 4 blocks/CU from actual usage.
__global__ __launch_bounds__(256, 2) void mfma_attn(
    const ushort* __restrict__ qb16, const ushort* __restrict__ kb16,
    const ushort* __restrict__ vtb, const float* __restrict__ kvg,
    const unsigned* __restrict__ sel, float* __restrict__ comb1,
    float* __restrict__ comb2) {
  const int qb = blockIdx.x, g = blockIdx.y;
  const int hg = blockIdx.z & 15, mode = blockIdx.z >> 4;
  const int tid = threadIdx.x, lane = tid & 63, w = tid >> 6;  // 4 waves
  const int quad = lane >> 4, l16 = lane & 15;
  const int head = g * 16 + hg;
  const int split = w;  // quarter of the key-block list
  const int t0 = qb * 64;

  __shared__ unsigned sel_s[64];
  __shared__ float pml[3][2][4][64];      // [w-1][m|l][qt][lane]  6 KB
  __shared__ short4_t pacc[3][4][4][64];  // [w-1][dt][qt][lane]  24 KB

  if (tid < 64) sel_s[tid] = sel[(size_t)(t0 + tid) * NG + g];
  __syncthreads();

  short8_t qB[4][2];
  #pragma unroll
  for (int qt = 0; qt < 4; ++qt)
    #pragma unroll
    for (int kd = 0; kd < 2; ++kd)
      qB[qt][kd] = *(const short8_t*)(qb16 +
          ((size_t)(t0 + qt * 16 + l16) * NHQ + head) * HD + kd * 32 + quad * 8);

  unsigned sbq[4];
  #pragma unroll
  for (int qt = 0; qt < 4; ++qt) sbq[qt] = sel_s[qt * 16 + l16];

  float m_[4], l_[4];
  f32x4 acc[4][4];
  const f32x4 fz = {0.f, 0.f, 0.f, 0.f};
  #pragma unroll
  for (int qt = 0; qt < 4; ++qt) { m_[qt] = -1e30f; l_[qt] = 0.f; }
  #pragma unroll
  for (int dt = 0; dt < 4; ++dt)
    #pragma unroll
    for (int qt = 0; qt < 4; ++qt) acc[dt][qt] = fz;

  // my quarter of the block list (interleaved for balance)
  unsigned mrem = 0; int b0 = 0, nb = 0;
  if (mode == 0) {
    unsigned uni = sel_s[lane];  // wave-parallel union OR-reduce
    #pragma unroll
    for (int off = 32; off >= 1; off >>= 1) uni |= __shfl_xor(uni, off);
    int cnt = 0;
    while (uni) {
      int b = __ffs(uni) - 1; uni &= uni - 1;
      if ((cnt++ & 3) == split) mrem |= 1u << b;
    }
    nb = __popc(mrem);
  } else {
    b0 = ((qb > 8) ? qb - 8 : 0) + split;
    nb = (qb >= b0) ? (qb - b0) / 4 + 1 : 0;
  }

  for (int ib = 0; ib < nb; ++ib) {
    int blk;
    if (mode == 0) { blk = __ffs(mrem) - 1; mrem &= mrem - 1; } else { blk = b0 + 4 * ib; }

    // S^T = K Q^T
    f32x4 sp[4][4];
    __builtin_amdgcn_s_setprio(1);
    #pragma unroll
    for (int kt = 0; kt < 4; ++kt) {
      const ushort* kr = kb16 + (size_t)(blk * 64 + kt * 16 + l16) * 128 + g * 64 + quad * 8;
      short8_t kA0 = *(const short8_t*)kr;
      short8_t kA1 = *(const short8_t*)(kr + 32);
      #pragma unroll
      for (int qt = 0; qt < 4; ++qt) {
        f32x4 c = __builtin_amdgcn_mfma_f32_16x16x32_bf16(kA0, qB[qt][0], fz, 0, 0, 0);
        sp[kt][qt] = __builtin_amdgcn_mfma_f32_16x16x32_bf16(kA1, qB[qt][1], c, 0, 0, 0);
      }
    }
    __builtin_amdgcn_s_setprio(0);

    const bool diag = (blk == qb);                     // causal mask needed
    const bool wedge = (mode == 1) && (blk == qb - 8); // window-edge mask

    short4_t pB[4][4];
    #pragma unroll
    for (int qt = 0; qt < 4; ++qt) {
      const int qg = t0 + qt * 16 + l16;
      const bool selq = (mode != 0) || (((sbq[qt] >> blk) & 1u) != 0);
      float mx = -INFINITY;
      if (!diag && !wedge) {
        // whole 64-key block valid iff selq (uniform across the 16 keys)
        const float scl = selq ? SCALE : 0.f;
        const float bia = selq ? 0.f : -INFINITY;
        #pragma unroll
        for (int kt = 0; kt < 4; ++kt)
          #pragma unroll
          for (int r = 0; r < 4; ++r) {
            float s_ = sp[kt][qt][r] * scl + bia;
            sp[kt][qt][r] = s_;
            mx = fmaxf(mx, s_);
          }
      } else {
        #pragma unroll
        for (int kt = 0; kt < 4; ++kt)
          #pragma unroll
          for (int r = 0; r < 4; ++r) {
            int key = blk * 64 + kt * 16 + quad * 4 + r;
            bool ok = selq && (key <= qg) && (qg - key <= 512);
            float s_ = ok ? sp[kt][qt][r] * SCALE : -INFINITY;
            sp[kt][qt][r] = s_;
            mx = fmaxf(mx, s_);
          }
      }
      mx = fmaxf(mx, __shfl_xor(mx, 16));
      mx = fmaxf(mx, __shfl_xor(mx, 32));
      float mold = m_[qt];
      if (!__all(mx <= mold + 8.f)) {  // T13 defer-max: rescale rarely
        float mnew = fmaxf(mold, mx);
        float alpha = __expf(mold - mnew);
        l_[qt] *= alpha;
        #pragma unroll
        for (int dt = 0; dt < 4; ++dt)
          #pragma unroll
          for (int r = 0; r < 4; ++r) acc[dt][qt][r] *= alpha;
        m_[qt] = mnew;
        mold = mnew;
      }
      float ps = 0.f;
      #pragma unroll
      for (int kt = 0; kt < 4; ++kt) {
        short4_t pb;
        #pragma unroll
        for (int r = 0; r < 4; ++r) {
          float p = __expf(sp[kt][qt][r] - mold);  // exp(-inf)=0; p <= e^8
          ps += p;
          pb[r] = pbf(p);
        }
        pB[kt][qt] = pb;
      }
      ps += __shfl_xor(ps, 16);
      ps += __shfl_xor(ps, 32);
      l_[qt] += ps;
    }

    // O^T += V^T P^T
    __builtin_amdgcn_s_setprio(1);
    #pragma unroll
    for (int kt = 0; kt < 4; ++kt) {
      short4_t vA[4];
      #pragma unroll
      for (int dt = 0; dt < 4; ++dt)
        vA[dt] = *(const short4_t*)(vtb +
            ((size_t)g * HD + dt * 16 + l16) * T_SEQ + blk * 64 + kt * 16 + quad * 4);
      #pragma unroll
      for (int dt = 0; dt < 4; ++dt)
        #pragma unroll
        for (int qt = 0; qt < 4; ++qt)
          acc[dt][qt] = __builtin_amdgcn_mfma_f32_16x16x16bf16_1k(
              vA[dt], pB[kt][qt], acc[dt][qt], 0, 0, 0);
    }
    __builtin_amdgcn_s_setprio(0);
  }

  // publish partials from waves 1..3, merge + epilogue in wave 0
  if (w > 0) {
    const int ws = w - 1;
    #pragma unroll
    for (int qt = 0; qt < 4; ++qt) {
      pml[ws][0][qt][lane] = m_[qt];
      pml[ws][1][qt][lane] = l_[qt];
    }
    #pragma unroll
    for (int dt = 0; dt < 4; ++dt)
      #pragma unroll
      for (int qt = 0; qt < 4; ++qt) {
        short4_t pk;
        #pragma unroll
        for (int r = 0; r < 4; ++r) pk[r] = (short)f2bf(acc[dt][qt][r]);
        pacc[ws][dt][qt][lane] = pk;
      }
  }
  __syncthreads();
  if (w == 0) {
    for (int s2 = 0; s2 < 3; ++s2) {
      float a1[4], a2[4];
      #pragma unroll
      for (int qt = 0; qt < 4; ++qt) {
        float m2 = pml[s2][0][qt][lane], l2 = pml[s2][1][qt][lane];
        float mN = fmaxf(m_[qt], m2);
        a1[qt] = __expf(m_[qt] - mN);
        a2[qt] = __expf(m2 - mN);
        l_[qt] = l_[qt] * a1[qt] + l2 * a2[qt];
        m_[qt] = mN;
      }
      #pragma unroll
      for (int dt = 0; dt < 4; ++dt)
        #pragma unroll
        for (int qt = 0; qt < 4; ++qt) {
          short4_t pk = pacc[s2][dt][qt][lane];
          #pragma unroll
          for (int r = 0; r < 4; ++r)
            acc[dt][qt][r] = acc[dt][qt][r] * a1[qt] + bf2f((ushort)pk[r]) * a2[qt];
        }
    }
    // epilogue
    #pragma unroll
    for (int qt = 0; qt < 4; ++qt) {
      const int t = t0 + qt * 16 + l16;
      const float c_ =
          (1.f / (1.f + __expf(-kvg[(size_t)t * KVGW + 257 + mode]))) / l_[qt];
      #pragma unroll
      for (int dt = 0; dt < 4; ++dt)
        #pragma unroll
        for (int r = 0; r < 4; ++r) {
          const int d = dt * 16 + quad * 4 + r;
          size_t idx = ((size_t)t * NHQ + head) * HD + d;
          if (mode == 0) comb1[idx] += c_ * acc[dt][qt][r];
          else           comb2[idx]  = c_ * acc[dt][qt][r];
        }
    }
  }
}

extern "C" void kernel_launch(void* const* d_in, const int* in_sizes, int n_in,
                              void* d_out, int out_size, void* d_ws, size_t ws_size,
                              hipStream_t stream) {
  const float* x   = (const float*)d_in[0];
  const float* Wq  = (const float*)d_in[1];
  const float* Wk  = (const float*)d_in[2];
  const float* Wv  = (const float*)d_in[3];
  const float* Wo  = (const float*)d_in[4];
  const float* Wg  = (const float*)d_in[5];
  const float* Wck = (const float*)d_in[6];
  const float* Wcv = (const float*)d_in[7];
  float* out = (float*)d_out;
  float* ws = (float*)d_ws;

  float* qbuf   = ws;                           // 4,194,304 f
  float* comb1  = qbuf + 4194304;               // 4,194,304 f
  float* kvg    = comb1 + 4194304;              //   786,432 f
  float* ckb    = kvg + 786432;                 //    16,384 f (bf16 ck+cvT)
  float* cvb    = ckb + 16384;                  //    16,384 f (unused)
  unsigned* sel = (unsigned*)(cvb + 16384);     //     4,096 u32
  ushort* kbf   = (ushort*)(sel + 4096);        //   262,144 u16
  ushort* vtb   = kbf + 262144;                 //   262,144 u16
  ushort* wkvgb = vtb + 262144;                 //   786,432 u16
  ushort* regA  = wkvgb + 786432;               // 4,194,304 u16: xb -> combb
  ushort* regB  = regA + 4194304;               // 4,194,304 u16: wqb -> qbf
  ushort* xb = regA;      ushort* combb = regA;
  ushort* wqb = regB;     ushort* qbf = regB;
  float* comb2 = qbuf;                // fp32 q dead after rope_all
  ushort* wob = (ushort*)qbuf;        // written after comb2 consumed

  ushort* ckb16 = (ushort*)ckb;       // 128*2*64 u16 = 32 KB
  ushort* cvtb  = ckb16 + 16384;      // 2*64*128 u16 = 32 KB (within ckb slot)

  const int CV = (4194304 + 255) / 256;
  cvt_bf<<<CV, 256, 0, stream>>>(x, xb, 4194304);
  cvt_bf<<<CV, 256, 0, stream>>>(Wq, wqb, 4194304);
  pack_wkvg<<<(KVGW * 2048 + 255) / 256, 256, 0, stream>>>(Wk, Wv, Wg, wkvgb);

  mgemm<<<dim3(16, 16), 256, 0, stream>>>(xb, wqb, qbuf, 2048, 2048, 2048);
  mgemm<<<dim3(3, 16), 256, 0, stream>>>(xb, wkvgb, kvg, 2048, KVGW, 2048);

  rope_all<<<2048, 256, 0, stream>>>(qbuf, kvg, qbf, kbf);
  cvt_vt<<<(262144 + 255) / 256, 256, 0, stream>>>(kvg, vtb);
  compress_kv<<<dim3(128, 2), 256, 0, stream>>>(kvg, Wck, Wcv, ckb16, cvtb);
  comp_attn<<<dim3(128, 2), 512, 0, stream>>>(qbf, ckb16, cvtb, kvg, comb1, sel);
  mfma_attn<<<dim3(32, 2, 32), 256, 0, stream>>>(qbf, kbf, vtb, kvg, sel, comb1, comb2);

  cvt_sum2_bf<<<CV, 256, 0, stream>>>(comb1, comb2, combb, 4194304);
  cvt_bf<<<CV, 256, 0, stream>>>(Wo, wob, 4194304);
  mgemm<<<dim3(16, 16), 256, 0, stream>>>(combb, wob, out, 2048, 2048, 2048);
}

// Round 5
// 430.394 us; speedup vs baseline: 1.8720x; 1.1505x over previous
//
#include <hip/hip_runtime.h>
#include <math.h>

#define T_SEQ 2048
#define NHQ 32
#define NG 2
#define HD 64
#define CSTRIDE 16
#define SCALE 0.125f
#define KVGW 384  // fused k|v|gate row width: 128 k + 128 v + 3 gate + pad

typedef __attribute__((ext_vector_type(8))) short short8_t;
typedef __attribute__((ext_vector_type(4))) short short4_t;
typedef __attribute__((ext_vector_type(4))) float f32x4;

__device__ __forceinline__ ushort f2bf(float x) {  // round-to-nearest-even
  union { float f; unsigned u; } c; c.f = x;
  unsigned r = c.u + 0x7fff + ((c.u >> 16) & 1);
  return (ushort)(r >> 16);
}
__device__ __forceinline__ short pbf(float x) {  // cheap round-half-up (x>=0)
  union { float f; unsigned u; } c; c.f = x;
  return (short)((c.u + 0x8000u) >> 16);
}
__device__ __forceinline__ float bf2f(ushort u) {
  union { unsigned u; float f; } c; c.u = ((unsigned)u) << 16;
  return c.f;
}

__device__ __forceinline__ void glds16(const ushort* g, ushort* l) {
  __builtin_amdgcn_global_load_lds(
      (const __attribute__((address_space(1))) unsigned int*)g,
      (__attribute__((address_space(3))) unsigned int*)l, 16, 0, 0);
}

// ---- bf16 MFMA GEMM: C[M,N] = A[M,K] * B[N,K]^T (m97 recipe + XOR swizzle)
__global__ __launch_bounds__(256) void mgemm(
    const ushort* __restrict__ A, const ushort* __restrict__ B,
    float* __restrict__ C, int M, int N, int K) {
  __shared__ __align__(16) ushort As[128 * 64];
  __shared__ __align__(16) ushort Bs[128 * 64];
  const int tid = threadIdx.x;
  const int lane = tid & 63, w = tid >> 6;
  const int quad = lane >> 4, l16 = lane & 15;
  const int m0 = blockIdx.y * 128, n0 = blockIdx.x * 128;
  const int mq = (w & 1) * 64, nq = (w >> 1) * 64;
  f32x4 acc[4][4];
  const f32x4 fz = {0.f, 0.f, 0.f, 0.f};
  #pragma unroll
  for (int i = 0; i < 4; ++i)
    #pragma unroll
    for (int j = 0; j < 4; ++j) acc[i][j] = fz;

  for (int k0 = 0; k0 < K; k0 += 64) {
    __syncthreads();
    #pragma unroll
    for (int j = 0; j < 4; ++j) {
      int ci = j * 256 + tid;
      int row = ci >> 3, cl = ci & 7;
      int kc = cl ^ (row & 7);
      glds16(A + ((size_t)(m0 + row) * K + k0 + kc * 8), &As[ci * 8]);
      glds16(B + ((size_t)(n0 + row) * K + k0 + kc * 8), &Bs[ci * 8]);
    }
    __syncthreads();
    #pragma unroll
    for (int kt = 0; kt < 2; ++kt) {
      short8_t af[4], bf_[4];
      #pragma unroll
      for (int mt = 0; mt < 4; ++mt) {
        int row = mq + mt * 16 + l16;
        int cl = (kt * 4 + quad) ^ (row & 7);
        af[mt] = *(const short8_t*)&As[row * 64 + cl * 8];
      }
      #pragma unroll
      for (int nt = 0; nt < 4; ++nt) {
        int row = nq + nt * 16 + l16;
        int cl = (kt * 4 + quad) ^ (row & 7);
        bf_[nt] = *(const short8_t*)&Bs[row * 64 + cl * 8];
      }
      #pragma unroll
      for (int mt = 0; mt < 4; ++mt)
        #pragma unroll
        for (int nt = 0; nt < 4; ++nt)
          acc[mt][nt] = __builtin_amdgcn_mfma_f32_16x16x32_bf16(
              af[mt], bf_[nt], acc[mt][nt], 0, 0, 0);
    }
  }
  #pragma unroll
  for (int mt = 0; mt < 4; ++mt)
    #pragma unroll
    for (int nt = 0; nt < 4; ++nt)
      #pragma unroll
      for (int r = 0; r < 4; ++r) {
        int m = m0 + mq + mt * 16 + quad * 4 + r;
        int n = n0 + nq + nt * 16 + l16;
        C[(size_t)m * N + n] = acc[mt][nt][r];
      }
}

// ---------------- conversions / packing ----------------
__global__ __launch_bounds__(256) void cvt_bf(const float* __restrict__ src,
                                              ushort* __restrict__ dst, int n) {
  int i = blockIdx.x * 256 + threadIdx.x;
  if (i < n) dst[i] = f2bf(src[i]);
}

__global__ __launch_bounds__(256) void cvt_sum2_bf(const float* __restrict__ a,
                                                   const float* __restrict__ b,
                                                   ushort* __restrict__ dst, int n) {
  int i = blockIdx.x * 256 + threadIdx.x;
  if (i < n) dst[i] = f2bf(a[i] + b[i]);
}

__global__ __launch_bounds__(256) void pack_wkvg(
    const float* __restrict__ Wk, const float* __restrict__ Wv,
    const float* __restrict__ Wg, ushort* __restrict__ dst) {
  int i = blockIdx.x * 256 + threadIdx.x;
  if (i >= KVGW * 2048) return;
  int n = i >> 11, k = i & 2047;
  float v;
  if (n < 128) v = Wk[(size_t)n * 2048 + k];
  else if (n < 256) v = Wv[(size_t)(n - 128) * 2048 + k];
  else if (n < 259) v = Wg[(size_t)(n - 256) * 2048 + k];
  else v = 0.f;
  dst[i] = f2bf(v);
}

// vt[g][d][s] bf16 from kvg v-part (v is NOT roped)
__global__ __launch_bounds__(256) void cvt_vt(const float* __restrict__ kvg,
                                              ushort* __restrict__ vt) {
  int i = blockIdx.x * 256 + threadIdx.x;
  if (i >= T_SEQ * NG * HD) return;
  int d = i & 63, g = (i >> 6) & 1, s = i >> 7;
  vt[((size_t)g * HD + d) * T_SEQ + s] =
      f2bf(kvg[(size_t)s * KVGW + 128 + g * 64 + d]);
}

// ------- RoPE: q fp32 -> qbf bf16; kvg k-part roped in place + kbf bf16 ----
__global__ __launch_bounds__(256) void rope_all(
    const float* __restrict__ q, float* __restrict__ kvg,
    ushort* __restrict__ qbf, ushort* __restrict__ kbf) {
  const int t = blockIdx.x;
  const float lnb_over = 9.210340371976184f / 32.f;  // ln(10000)/32
  for (int job = threadIdx.x; job < (NHQ + NG) * 32; job += 256) {
    int h = job >> 5, j = job & 31;
    float inv = expf(-(float)j * lnb_over);
    float fr = (float)t * inv;
    float c_ = cosf(fr), s_ = sinf(fr);
    if (h < NHQ) {
      const float* base = q + ((size_t)t * NHQ + h) * HD;
      float x1 = base[j], x2 = base[j + 32];
      ushort* ob = qbf + ((size_t)t * NHQ + h) * HD;
      ob[j] = f2bf(x1 * c_ - x2 * s_);
      ob[j + 32] = f2bf(x2 * c_ + x1 * s_);
    } else {
      int g = h - NHQ;
      float* base = kvg + (size_t)t * KVGW + g * 64;
      float x1 = base[j], x2 = base[j + 32];
      float o1 = x1 * c_ - x2 * s_, o2 = x2 * c_ + x1 * s_;
      base[j] = o1; base[j + 32] = o2;
      kbf[(size_t)t * 128 + g * 64 + j] = f2bf(o1);
      kbf[(size_t)t * 128 + g * 64 + j + 32] = f2bf(o2);
    }
  }
}

// ------- compression: bf16 ck[c][g][d] and transposed bf16 cv^T[g][d][c] ---
// grid (128, 2); c==127 writes the zero pad row (c is padded 127 -> 128).
__global__ __launch_bounds__(256) void compress_kv(
    const float* __restrict__ kvg,
    const float* __restrict__ Wck, const float* __restrict__ Wcv,
    ushort* __restrict__ ck16, ushort* __restrict__ cvt16) {
  const int c = blockIdx.x, g = blockIdx.y;
  const int tid = threadIdx.x;
  if (c == 127) {  // zero pad so MFMA never touches garbage
    if (tid < 64) ck16[((size_t)127 * NG + g) * HD + tid] = 0;
    else if (tid < 128) cvt16[((size_t)g * HD + (tid - 64)) * 128 + 127] = 0;
    return;
  }
  const int d = tid & 63, chunk = tid >> 6;
  __shared__ float red[2][4][64];
  float ak = 0.f, av = 0.f;
  for (int f = chunk * 512; f < chunk * 512 + 512; ++f) {
    int i = f >> 6, e = f & 63;
    int trow = c * CSTRIDE + i;
    float kv = kvg[(size_t)trow * KVGW + g * 64 + e];
    float vv = kvg[(size_t)trow * KVGW + 128 + g * 64 + e];
    ak += kv * Wck[((size_t)g * 2048 + f) * HD + d];
    av += vv * Wcv[((size_t)g * 2048 + f) * HD + d];
  }
  red[0][chunk][d] = ak;
  red[1][chunk][d] = av;
  __syncthreads();
  if (tid < 64) {
    ck16[((size_t)c * NG + g) * HD + tid] =
        f2bf(red[0][0][tid] + red[0][1][tid] + red[0][2][tid] + red[0][3][tid]);
  } else if (tid < 128) {
    int dd = tid - 64;
    cvt16[((size_t)g * HD + dd) * 128 + c] =
        f2bf(red[1][0][dd] + red[1][1][dd] + red[1][2][dd] + red[1][3][dd]);
  }
}

// ------- MFMA compressed attention + block scores + parallel top-16 -------
// grid (128 t-tiles of 16, 2 g), 512 threads = 8 waves x 2 heads each.
__global__ __launch_bounds__(512) void comp_attn(
    const ushort* __restrict__ qbf, const ushort* __restrict__ ck16,
    const ushort* __restrict__ cvt16, const float* __restrict__ kvg,
    float* __restrict__ comb, unsigned* __restrict__ sel) {
  const int tb = blockIdx.x, g = blockIdx.y;
  const int t0 = tb * 16;
  const int tid = threadIdx.x, lane = tid & 63, w = tid >> 6;
  const int quad = lane >> 4, l16 = lane & 15;
  const int qb = t0 >> 6;  // uniform across the 16 t's of this block

  __shared__ float colsum[16][129];  // [t_local][c], padded vs bank conflicts
  for (int i = tid; i < 16 * 129; i += 512) ((float*)colsum)[i] = 0.f;
  __syncthreads();

  const int t = t0 + l16;
  const int cmaxv = (t >= 31) ? min(126, (t - 31) >> 4) : -1;
  const int h0 = w * 2;  // two heads per wave

  short8_t qB[2][2];
  #pragma unroll
  for (int hh = 0; hh < 2; ++hh)
    #pragma unroll
    for (int kd = 0; kd < 2; ++kd)
      qB[hh][kd] = *(const short8_t*)(qbf +
          ((size_t)t * NHQ + g * 16 + h0 + hh) * HD + kd * 32 + quad * 8);

  const f32x4 fz = {0.f, 0.f, 0.f, 0.f};
  f32x4 sp[2][8];

  #pragma unroll
  for (int ct = 0; ct < 8; ++ct) {
    const ushort* kr = ck16 + ((size_t)(ct * 16 + l16) * NG + g) * HD + quad * 8;
    short8_t kA0 = *(const short8_t*)kr;
    short8_t kA1 = *(const short8_t*)(kr + 32);
    #pragma unroll
    for (int hh = 0; hh < 2; ++hh) {
      f32x4 c0 = __builtin_amdgcn_mfma_f32_16x16x32_bf16(kA0, qB[hh][0], fz, 0, 0, 0);
      sp[hh][ct] = __builtin_amdgcn_mfma_f32_16x16x32_bf16(kA1, qB[hh][1], c0, 0, 0, 0);
    }
  }

  short4_t pB[2][8];
  #pragma unroll
  for (int hh = 0; hh < 2; ++hh) {
    float mx = -INFINITY;
    #pragma unroll
    for (int ct = 0; ct < 8; ++ct)
      #pragma unroll
      for (int r = 0; r < 4; ++r) {
        int c = ct * 16 + quad * 4 + r;
        float s_ = (c <= cmaxv) ? sp[hh][ct][r] * SCALE : -INFINITY;
        sp[hh][ct][r] = s_;
        mx = fmaxf(mx, s_);
      }
    mx = fmaxf(mx, __shfl_xor(mx, 16));
    mx = fmaxf(mx, __shfl_xor(mx, 32));
    if (mx == -INFINITY) mx = 0.f;  // fully-masked rows (t < 31)
    float ls = 0.f;
    #pragma unroll
    for (int ct = 0; ct < 8; ++ct)
      #pragma unroll
      for (int r = 0; r < 4; ++r) {
        float p = __expf(sp[hh][ct][r] - mx);
        sp[hh][ct][r] = p;
        ls += p;
      }
    ls += __shfl_xor(ls, 16);
    ls += __shfl_xor(ls, 32);
    float inv = (ls > 0.f) ? 1.f / ls : 0.f;
    #pragma unroll
    for (int ct = 0; ct < 8; ++ct) {
      short4_t pk;
      #pragma unroll
      for (int r = 0; r < 4; ++r) {
        float pn = sp[hh][ct][r] * inv;
        sp[hh][ct][r] = pn;
        pk[r] = (short)f2bf(pn);
      }
      pB[hh][ct] = pk;
    }
  }

  #pragma unroll
  for (int ct = 0; ct < 8; ++ct)
    #pragma unroll
    for (int r = 0; r < 4; ++r)
      atomicAdd(&colsum[l16][ct * 16 + quad * 4 + r],
                sp[0][ct][r] + sp[1][ct][r]);

  f32x4 acc[2][4];
  #pragma unroll
  for (int hh = 0; hh < 2; ++hh)
    #pragma unroll
    for (int dt = 0; dt < 4; ++dt) acc[hh][dt] = fz;
  #pragma unroll
  for (int ct = 0; ct < 8; ++ct) {
    short4_t vA[4];
    #pragma unroll
    for (int dt = 0; dt < 4; ++dt)
      vA[dt] = *(const short4_t*)(cvt16 +
          ((size_t)g * HD + dt * 16 + l16) * 128 + ct * 16 + quad * 4);
    #pragma unroll
    for (int hh = 0; hh < 2; ++hh)
      #pragma unroll
      for (int dt = 0; dt < 4; ++dt)
        acc[hh][dt] = __builtin_amdgcn_mfma_f32_16x16x16bf16_1k(
            vA[dt], pB[hh][ct], acc[hh][dt], 0, 0, 0);
  }

  const float g0 = 1.f / (1.f + __expf(-kvg[(size_t)t * KVGW + 256]));
  #pragma unroll
  for (int hh = 0; hh < 2; ++hh)
    #pragma unroll
    for (int dt = 0; dt < 4; ++dt)
      #pragma unroll
      for (int r = 0; r < 4; ++r)
        comb[((size_t)t * NHQ + g * 16 + h0 + hh) * HD + dt * 16 + quad * 4 + r] =
            g0 * acc[hh][dt][r];

  __syncthreads();

  {
    const int tl = tid >> 5;   // 0..15
    const int b = tid & 31;
    float s;
    if (b > qb) s = -INFINITY;
    else if (b == 0 || qb - b < 2) s = INFINITY;
    else {
      s = 0.f;
      #pragma unroll
      for (int i = 0; i < 5; ++i) s += colsum[tl][4 * b - 1 + i];
    }
    unsigned key = (s < 0.f) ? 0u : (__float_as_uint(s) + 1u);
    unsigned msel = 0;
    for (int it = 0; it < 16; ++it) {
      unsigned long long pk =
          (((unsigned long long)key) << 6) | (unsigned)(63 - b);
      #pragma unroll
      for (int off = 16; off >= 1; off >>= 1) {
        unsigned long long o = __shfl_xor(pk, off);
        if (o > pk) pk = o;
      }
      if ((pk >> 6) == 0) break;  // uniform within the 32-group
      int bs = 63 - (int)(pk & 63);
      msel |= 1u << bs;
      if (b == bs) key = 0;
    }
    if (b == 0) sel[(size_t)(t0 + tl) * NG + g] = msel;
  }
}

// ------- MFMA flash attention v5: query-split waves + LDS-staged K/V -------
// 256 thr = 4 waves; wave w owns queries t0+w*16..+15 of ONE head.
// All waves iterate the SAME key-block list, so K (64x64) and V^T (64x64)
// tiles are cooperatively staged into LDS via coalesced glds16 (16 B/lane),
// double-buffered: STAGE(next) issued before compute(cur), one
// __syncthreads per iter (2-phase pattern; barrier drains vmcnt).
// XOR chunk-swizzle (mgemm recipe, rule 21): linear LDS dest, inverse-
// swizzled global source, swizzled ds_read -> stride-128B rows bank-clean.
// No split-K -> no merge phase, no pml/pacc LDS, exact fp32 accumulate.
// grid (32 qb, 2 g, 32 = 16 hg x 2 mode). (256,2): 128-VGPR cap (no spill;
// (*,4) variants cap at 64 VGPR and spill ~1GB - round-3 disaster).
__global__ __launch_bounds__(256, 2) void mfma_attn(
    const ushort* __restrict__ qb16, const ushort* __restrict__ kb16,
    const ushort* __restrict__ vtb, const float* __restrict__ kvg,
    const unsigned* __restrict__ sel, float* __restrict__ comb1,
    float* __restrict__ comb2) {
  const int qb = blockIdx.x, g = blockIdx.y;
  const int hg = blockIdx.z & 15, mode = blockIdx.z >> 4;
  const int tid = threadIdx.x, lane = tid & 63, w = tid >> 6;  // 4 waves
  const int quad = lane >> 4, l16 = lane & 15;
  const int head = g * 16 + hg;
  const int t0 = qb * 64;

  __shared__ __align__(16) ushort Ks[2][64 * 64];  // 16 KB (dbuf)
  __shared__ __align__(16) ushort Vs[2][64 * 64];  // 16 KB (dbuf)
  __shared__ unsigned sel_s[64];

  if (tid < 64) sel_s[tid] = sel[(size_t)(t0 + tid) * NG + g];
  __syncthreads();

  // my 16 queries (one 16-row tile per wave)
  const int qg = t0 + w * 16 + l16;
  const unsigned sbq = sel_s[w * 16 + l16];

  short8_t qB0 = *(const short8_t*)(qb16 +
      ((size_t)qg * NHQ + head) * HD + quad * 8);
  short8_t qB1 = *(const short8_t*)(qb16 +
      ((size_t)qg * NHQ + head) * HD + 32 + quad * 8);

  float m_ = -1e30f, l_ = 0.f;
  f32x4 acc[4];
  const f32x4 fz = {0.f, 0.f, 0.f, 0.f};
  #pragma unroll
  for (int dt = 0; dt < 4; ++dt) acc[dt] = fz;

  // full key-block list (same for all 4 waves)
  unsigned mrem = 0; int b0 = 0, nb = 0;
  if (mode == 0) {
    unsigned uni = sel_s[lane];  // wave-parallel union OR-reduce
    #pragma unroll
    for (int off = 32; off >= 1; off >>= 1) uni |= __shfl_xor(uni, off);
    mrem = uni;
    nb = __popc(mrem);
  } else {
    b0 = (qb > 8) ? qb - 8 : 0;
    nb = qb - b0 + 1;
  }

  // stage key-block blk's K (64 keys x 64 dims) and V^T (64 dims x 64 keys)
  // tiles into LDS buf: 2+2 coalesced 16B chunks per thread, source chunk
  // XOR-permuted so swizzled reads see source chunk s at dst chunk s^(row&7).
  #define STAGE(buf, blk)                                                     \
    {                                                                         \
      const int blk_ = (blk);                                                 \
      _Pragma("unroll")                                                       \
      for (int j = 0; j < 2; ++j) {                                           \
        int ci = j * 256 + tid;                                               \
        int row = ci >> 3, cl = ci & 7;                                       \
        int kc = cl ^ (row & 7);                                              \
        glds16(kb16 + (size_t)(blk_ * 64 + row) * 128 + g * 64 + kc * 8,      \
               &Ks[buf][ci * 8]);                                             \
        glds16(vtb + ((size_t)g * 64 + row) * 2048 + blk_ * 64 + kc * 8,      \
               &Vs[buf][ci * 8]);                                             \
      }                                                                       \
    }

  int blkcur;
  if (mode == 0) { blkcur = __ffs(mrem) - 1; mrem &= mrem - 1; }
  else blkcur = b0;
  STAGE(0, blkcur);
  __syncthreads();  // drains vmcnt(0): tile 0 resident

  const int e = l16 & 7;  // row&7 for all fragment rows (kt*16/dt*16 = 0 mod 8)

  for (int ib = 0; ib < nb; ++ib) {
    const int cur = ib & 1;
    const int blk = blkcur;
    if (ib + 1 < nb) {  // prefetch next tile into other buffer
      if (mode == 0) { blkcur = __ffs(mrem) - 1; mrem &= mrem - 1; }
      else blkcur = b0 + ib + 1;
      STAGE(cur ^ 1, blkcur);
    }

    // S^T = K Q^T from LDS (swizzled reads; 16B aligned)
    f32x4 sp[4];
    __builtin_amdgcn_s_setprio(1);
    #pragma unroll
    for (int kt = 0; kt < 4; ++kt) {
      const ushort* kr = &Ks[cur][(kt * 16 + l16) * 64];
      short8_t kA0 = *(const short8_t*)(kr + ((quad ^ e) * 8));
      short8_t kA1 = *(const short8_t*)(kr + ((quad ^ e ^ 4) * 8));
      f32x4 c = __builtin_amdgcn_mfma_f32_16x16x32_bf16(kA0, qB0, fz, 0, 0, 0);
      sp[kt] = __builtin_amdgcn_mfma_f32_16x16x32_bf16(kA1, qB1, c, 0, 0, 0);
    }
    __builtin_amdgcn_s_setprio(0);

    const bool diag = (blk == qb);                     // causal mask needed
    const bool wedge = (mode == 1) && (blk == qb - 8); // window-edge mask
    const bool selq = (mode != 0) || (((sbq >> blk) & 1u) != 0);

    float mx = -INFINITY;
    if (!diag && !wedge) {
      // whole 64-key block valid iff selq (uniform across this query's keys)
      const float scl = selq ? SCALE : 0.f;
      const float bia = selq ? 0.f : -INFINITY;
      #pragma unroll
      for (int kt = 0; kt < 4; ++kt)
        #pragma unroll
        for (int r = 0; r < 4; ++r) {
          float s_ = sp[kt][r] * scl + bia;
          sp[kt][r] = s_;
          mx = fmaxf(mx, s_);
        }
    } else {
      #pragma unroll
      for (int kt = 0; kt < 4; ++kt)
        #pragma unroll
        for (int r = 0; r < 4; ++r) {
          int key = blk * 64 + kt * 16 + quad * 4 + r;
          bool ok = selq && (key <= qg) && (qg - key <= 512);
          float s_ = ok ? sp[kt][r] * SCALE : -INFINITY;
          sp[kt][r] = s_;
          mx = fmaxf(mx, s_);
        }
    }
    mx = fmaxf(mx, __shfl_xor(mx, 16));
    mx = fmaxf(mx, __shfl_xor(mx, 32));
    float mold = m_;
    if (!__all(mx <= mold + 8.f)) {  // T13 defer-max: rescale rarely
      float mnew = fmaxf(mold, mx);
      float alpha = __expf(mold - mnew);
      l_ *= alpha;
      #pragma unroll
      for (int dt = 0; dt < 4; ++dt)
        #pragma unroll
        for (int r = 0; r < 4; ++r) acc[dt][r] *= alpha;
      m_ = mnew;
      mold = mnew;
    }
    short4_t pB[4];
    float ps = 0.f;
    #pragma unroll
    for (int kt = 0; kt < 4; ++kt) {
      short4_t pb;
      #pragma unroll
      for (int r = 0; r < 4; ++r) {
        float p = __expf(sp[kt][r] - mold);  // exp(-inf)=0; p <= e^8
        ps += p;
        pb[r] = pbf(p);
      }
      pB[kt] = pb;
    }
    ps += __shfl_xor(ps, 16);
    ps += __shfl_xor(ps, 32);
    l_ += ps;

    // O^T += V^T P^T from LDS
    __builtin_amdgcn_s_setprio(1);
    #pragma unroll
    for (int kt = 0; kt < 4; ++kt) {
      const int sc = kt * 2 + (quad >> 1);  // source 16B chunk of this 8B read
      #pragma unroll
      for (int dt = 0; dt < 4; ++dt) {
        short4_t vA = *(const short4_t*)(&Vs[cur][(dt * 16 + l16) * 64 +
                                                  ((sc ^ e) * 8) + (quad & 1) * 4]);
        acc[dt] = __builtin_amdgcn_mfma_f32_16x16x16bf16_1k(
            vA, pB[kt], acc[dt], 0, 0, 0);
      }
    }
    __builtin_amdgcn_s_setprio(0);

    __syncthreads();  // all reads of buf[cur] done; next STAGE may overwrite
  }
  #undef STAGE

  // epilogue: each wave owns its 16 queries — no merge needed
  const float c_ =
      (1.f / (1.f + __expf(-kvg[(size_t)qg * KVGW + 257 + mode]))) / l_;
  #pragma unroll
  for (int dt = 0; dt < 4; ++dt)
    #pragma unroll
    for (int r = 0; r < 4; ++r) {
      const int d = dt * 16 + quad * 4 + r;
      size_t idx = ((size_t)qg * NHQ + head) * HD + d;
      if (mode == 0) comb1[idx] += c_ * acc[dt][r];
      else           comb2[idx]  = c_ * acc[dt][r];
    }
}

extern "C" void kernel_launch(void* const* d_in, const int* in_sizes, int n_in,
                              void* d_out, int out_size, void* d_ws, size_t ws_size,
                              hipStream_t stream) {
  const float* x   = (const float*)d_in[0];
  const float* Wq  = (const float*)d_in[1];
  const float* Wk  = (const float*)d_in[2];
  const float* Wv  = (const float*)d_in[3];
  const float* Wo  = (const float*)d_in[4];
  const float* Wg  = (const float*)d_in[5];
  const float* Wck = (const float*)d_in[6];
  const float* Wcv = (const float*)d_in[7];
  float* out = (float*)d_out;
  float* ws = (float*)d_ws;

  float* qbuf   = ws;                           // 4,194,304 f
  float* comb1  = qbuf + 4194304;               // 4,194,304 f
  float* kvg    = comb1 + 4194304;              //   786,432 f
  float* ckb    = kvg + 786432;                 //    16,384 f (bf16 ck+cvT)
  float* cvb    = ckb + 16384;                  //    16,384 f (unused)
  unsigned* sel = (unsigned*)(cvb + 16384);     //     4,096 u32
  ushort* kbf   = (ushort*)(sel + 4096);        //   262,144 u16
  ushort* vtb   = kbf + 262144;                 //   262,144 u16
  ushort* wkvgb = vtb + 262144;                 //   786,432 u16
  ushort* regA  = wkvgb + 786432;               // 4,194,304 u16: xb -> combb
  ushort* regB  = regA + 4194304;               // 4,194,304 u16: wqb -> qbf
  ushort* xb = regA;      ushort* combb = regA;
  ushort* wqb = regB;     ushort* qbf = regB;
  float* comb2 = qbuf;                // fp32 q dead after rope_all
  ushort* wob = (ushort*)qbuf;        // written after comb2 consumed

  ushort* ckb16 = (ushort*)ckb;       // 128*2*64 u16 = 32 KB
  ushort* cvtb  = ckb16 + 16384;      // 2*64*128 u16 = 32 KB (within ckb slot)

  const int CV = (4194304 + 255) / 256;
  cvt_bf<<<CV, 256, 0, stream>>>(x, xb, 4194304);
  cvt_bf<<<CV, 256, 0, stream>>>(Wq, wqb, 4194304);
  pack_wkvg<<<(KVGW * 2048 + 255) / 256, 256, 0, stream>>>(Wk, Wv, Wg, wkvgb);

  mgemm<<<dim3(16, 16), 256, 0, stream>>>(xb, wqb, qbuf, 2048, 2048, 2048);
  mgemm<<<dim3(3, 16), 256, 0, stream>>>(xb, wkvgb, kvg, 2048, KVGW, 2048);

  rope_all<<<2048, 256, 0, stream>>>(qbuf, kvg, qbf, kbf);
  cvt_vt<<<(262144 + 255) / 256, 256, 0, stream>>>(kvg, vtb);
  compress_kv<<<dim3(128, 2), 256, 0, stream>>>(kvg, Wck, Wcv, ckb16, cvtb);
  comp_attn<<<dim3(128, 2), 512, 0, stream>>>(qbf, ckb16, cvtb, kvg, comb1, sel);
  mfma_attn<<<dim3(32, 2, 32), 256, 0, stream>>>(qbf, kbf, vtb, kvg, sel, comb1, comb2);

  cvt_sum2_bf<<<CV, 256, 0, stream>>>(comb1, comb2, combb, 4194304);
  cvt_bf<<<CV, 256, 0, stream>>>(Wo, wob, 4194304);
  mgemm<<<dim3(16, 16), 256, 0, stream>>>(combb, wob, out, 2048, 2048, 2048);
}

// Round 6
// 421.420 us; speedup vs baseline: 1.9119x; 1.0213x over previous
//
#include <hip/hip_runtime.h>
#include <math.h>

#define T_SEQ 2048
#define NHQ 32
#define NG 2
#define HD 64
#define CSTRIDE 16
#define KVGW 384  // fused k|v|gate row width: 128 k + 128 v + 3 gate + pad

typedef __attribute__((ext_vector_type(8))) short short8_t;
typedef __attribute__((ext_vector_type(4))) short short4_t;
typedef __attribute__((ext_vector_type(4))) float f32x4;

__device__ __forceinline__ ushort f2bf(float x) {  // round-to-nearest-even
  union { float f; unsigned u; } c; c.f = x;
  unsigned r = c.u + 0x7fff + ((c.u >> 16) & 1);
  return (ushort)(r >> 16);
}
__device__ __forceinline__ float bf2f(ushort u) {
  union { unsigned u; float f; } c; c.u = ((unsigned)u) << 16;
  return c.f;
}

__device__ __forceinline__ void glds16(const ushort* g, ushort* l) {
  __builtin_amdgcn_global_load_lds(
      (const __attribute__((address_space(1))) unsigned int*)g,
      (__attribute__((address_space(3))) unsigned int*)l, 16, 0, 0);
}

// ---- bf16 MFMA GEMM: C[M,N] = A[M,K] * B[N,K]^T (m97 recipe + XOR swizzle)
__global__ __launch_bounds__(256) void mgemm(
    const ushort* __restrict__ A, const ushort* __restrict__ B,
    float* __restrict__ C, int M, int N, int K) {
  __shared__ __align__(16) ushort As[128 * 64];
  __shared__ __align__(16) ushort Bs[128 * 64];
  const int tid = threadIdx.x;
  const int lane = tid & 63, w = tid >> 6;
  const int quad = lane >> 4, l16 = lane & 15;
  const int m0 = blockIdx.y * 128, n0 = blockIdx.x * 128;
  const int mq = (w & 1) * 64, nq = (w >> 1) * 64;
  f32x4 acc[4][4];
  const f32x4 fz = {0.f, 0.f, 0.f, 0.f};
  #pragma unroll
  for (int i = 0; i < 4; ++i)
    #pragma unroll
    for (int j = 0; j < 4; ++j) acc[i][j] = fz;

  for (int k0 = 0; k0 < K; k0 += 64) {
    __syncthreads();
    #pragma unroll
    for (int j = 0; j < 4; ++j) {
      int ci = j * 256 + tid;
      int row = ci >> 3, cl = ci & 7;
      int kc = cl ^ (row & 7);
      glds16(A + ((size_t)(m0 + row) * K + k0 + kc * 8), &As[ci * 8]);
      glds16(B + ((size_t)(n0 + row) * K + k0 + kc * 8), &Bs[ci * 8]);
    }
    __syncthreads();
    #pragma unroll
    for (int kt = 0; kt < 2; ++kt) {
      short8_t af[4], bf_[4];
      #pragma unroll
      for (int mt = 0; mt < 4; ++mt) {
        int row = mq + mt * 16 + l16;
        int cl = (kt * 4 + quad) ^ (row & 7);
        af[mt] = *(const short8_t*)&As[row * 64 + cl * 8];
      }
      #pragma unroll
      for (int nt = 0; nt < 4; ++nt) {
        int row = nq + nt * 16 + l16;
        int cl = (kt * 4 + quad) ^ (row & 7);
        bf_[nt] = *(const short8_t*)&Bs[row * 64 + cl * 8];
      }
      #pragma unroll
      for (int mt = 0; mt < 4; ++mt)
        #pragma unroll
        for (int nt = 0; nt < 4; ++nt)
          acc[mt][nt] = __builtin_amdgcn_mfma_f32_16x16x32_bf16(
              af[mt], bf_[nt], acc[mt][nt], 0, 0, 0);
    }
  }
  #pragma unroll
  for (int mt = 0; mt < 4; ++mt)
    #pragma unroll
    for (int nt = 0; nt < 4; ++nt)
      #pragma unroll
      for (int r = 0; r < 4; ++r) {
        int m = m0 + mq + mt * 16 + quad * 4 + r;
        int n = n0 + nq + nt * 16 + l16;
        C[(size_t)m * N + n] = acc[mt][nt][r];
      }
}

// ---------------- conversions / packing ----------------
__global__ __launch_bounds__(256) void cvt_bf(const float* __restrict__ src,
                                              ushort* __restrict__ dst, int n) {
  int i = blockIdx.x * 256 + threadIdx.x;
  if (i < n) dst[i] = f2bf(src[i]);
}

__global__ __launch_bounds__(256) void cvt_sum2_bf(const float* __restrict__ a,
                                                   const float* __restrict__ b,
                                                   ushort* __restrict__ dst, int n) {
  int i = blockIdx.x * 256 + threadIdx.x;
  if (i < n) dst[i] = f2bf(a[i] + b[i]);
}

__global__ __launch_bounds__(256) void pack_wkvg(
    const float* __restrict__ Wk, const float* __restrict__ Wv,
    const float* __restrict__ Wg, ushort* __restrict__ dst) {
  int i = blockIdx.x * 256 + threadIdx.x;
  if (i >= KVGW * 2048) return;
  int n = i >> 11, k = i & 2047;
  float v;
  if (n < 128) v = Wk[(size_t)n * 2048 + k];
  else if (n < 256) v = Wv[(size_t)(n - 128) * 2048 + k];
  else if (n < 259) v = Wg[(size_t)(n - 256) * 2048 + k];
  else v = 0.f;
  dst[i] = f2bf(v);
}

// vt[g][d][s] bf16 from kvg v-part (v is NOT roped)
__global__ __launch_bounds__(256) void cvt_vt(const float* __restrict__ kvg,
                                              ushort* __restrict__ vt) {
  int i = blockIdx.x * 256 + threadIdx.x;
  if (i >= T_SEQ * NG * HD) return;
  int d = i & 63, g = (i >> 6) & 1, s = i >> 7;
  vt[((size_t)g * HD + d) * T_SEQ + s] =
      f2bf(kvg[(size_t)s * KVGW + 128 + g * 64 + d]);
}

// ------- RoPE: q fp32 -> qbf bf16 PRE-SCALED by 1/8 (exact exponent shift,
// lossless in bf16; lets attention kernels drop the per-score SCALE mul).
// kvg k-part roped in place + kbf bf16 (NOT scaled).
__global__ __launch_bounds__(256) void rope_all(
    const float* __restrict__ q, float* __restrict__ kvg,
    ushort* __restrict__ qbf, ushort* __restrict__ kbf) {
  const int t = blockIdx.x;
  const float lnb_over = 9.210340371976184f / 32.f;  // ln(10000)/32
  for (int job = threadIdx.x; job < (NHQ + NG) * 32; job += 256) {
    int h = job >> 5, j = job & 31;
    float inv = expf(-(float)j * lnb_over);
    float fr = (float)t * inv;
    float c_ = cosf(fr), s_ = sinf(fr);
    if (h < NHQ) {
      const float cq = c_ * 0.125f, sq = s_ * 0.125f;
      const float* base = q + ((size_t)t * NHQ + h) * HD;
      float x1 = base[j], x2 = base[j + 32];
      ushort* ob = qbf + ((size_t)t * NHQ + h) * HD;
      ob[j] = f2bf(x1 * cq - x2 * sq);
      ob[j + 32] = f2bf(x2 * cq + x1 * sq);
    } else {
      int g = h - NHQ;
      float* base = kvg + (size_t)t * KVGW + g * 64;
      float x1 = base[j], x2 = base[j + 32];
      float o1 = x1 * c_ - x2 * s_, o2 = x2 * c_ + x1 * s_;
      base[j] = o1; base[j + 32] = o2;
      kbf[(size_t)t * 128 + g * 64 + j] = f2bf(o1);
      kbf[(size_t)t * 128 + g * 64 + j + 32] = f2bf(o2);
    }
  }
}

// ------- compression: bf16 ck[c][g][d] and transposed bf16 cv^T[g][d][c] ---
// grid (128, 2); c==127 writes the zero pad row (c is padded 127 -> 128).
__global__ __launch_bounds__(256) void compress_kv(
    const float* __restrict__ kvg,
    const float* __restrict__ Wck, const float* __restrict__ Wcv,
    ushort* __restrict__ ck16, ushort* __restrict__ cvt16) {
  const int c = blockIdx.x, g = blockIdx.y;
  const int tid = threadIdx.x;
  if (c == 127) {  // zero pad so MFMA never touches garbage
    if (tid < 64) ck16[((size_t)127 * NG + g) * HD + tid] = 0;
    else if (tid < 128) cvt16[((size_t)g * HD + (tid - 64)) * 128 + 127] = 0;
    return;
  }
  const int d = tid & 63, chunk = tid >> 6;
  __shared__ float red[2][4][64];
  float ak = 0.f, av = 0.f;
  for (int f = chunk * 512; f < chunk * 512 + 512; ++f) {
    int i = f >> 6, e = f & 63;
    int trow = c * CSTRIDE + i;
    float kv = kvg[(size_t)trow * KVGW + g * 64 + e];
    float vv = kvg[(size_t)trow * KVGW + 128 + g * 64 + e];
    ak += kv * Wck[((size_t)g * 2048 + f) * HD + d];
    av += vv * Wcv[((size_t)g * 2048 + f) * HD + d];
  }
  red[0][chunk][d] = ak;
  red[1][chunk][d] = av;
  __syncthreads();
  if (tid < 64) {
    ck16[((size_t)c * NG + g) * HD + tid] =
        f2bf(red[0][0][tid] + red[0][1][tid] + red[0][2][tid] + red[0][3][tid]);
  } else if (tid < 128) {
    int dd = tid - 64;
    cvt16[((size_t)g * HD + dd) * 128 + c] =
        f2bf(red[1][0][dd] + red[1][1][dd] + red[1][2][dd] + red[1][3][dd]);
  }
}

// ------- MFMA compressed attention + block scores + parallel top-16 -------
// grid (128 t-tiles of 16, 2 g), 512 threads = 8 waves x 2 heads each.
// q is pre-scaled by 1/8 (rope_all), so scores need no SCALE mul.
__global__ __launch_bounds__(512) void comp_attn(
    const ushort* __restrict__ qbf, const ushort* __restrict__ ck16,
    const ushort* __restrict__ cvt16, const float* __restrict__ kvg,
    float* __restrict__ comb, unsigned* __restrict__ sel) {
  const int tb = blockIdx.x, g = blockIdx.y;
  const int t0 = tb * 16;
  const int tid = threadIdx.x, lane = tid & 63, w = tid >> 6;
  const int quad = lane >> 4, l16 = lane & 15;
  const int qb = t0 >> 6;  // uniform across the 16 t's of this block

  __shared__ float colsum[16][129];  // [t_local][c], padded vs bank conflicts
  for (int i = tid; i < 16 * 129; i += 512) ((float*)colsum)[i] = 0.f;
  __syncthreads();

  const int t = t0 + l16;
  const int cmaxv = (t >= 31) ? min(126, (t - 31) >> 4) : -1;
  const int h0 = w * 2;  // two heads per wave

  short8_t qB[2][2];
  #pragma unroll
  for (int hh = 0; hh < 2; ++hh)
    #pragma unroll
    for (int kd = 0; kd < 2; ++kd)
      qB[hh][kd] = *(const short8_t*)(qbf +
          ((size_t)t * NHQ + g * 16 + h0 + hh) * HD + kd * 32 + quad * 8);

  const f32x4 fz = {0.f, 0.f, 0.f, 0.f};
  f32x4 sp[2][8];

  #pragma unroll
  for (int ct = 0; ct < 8; ++ct) {
    const ushort* kr = ck16 + ((size_t)(ct * 16 + l16) * NG + g) * HD + quad * 8;
    short8_t kA0 = *(const short8_t*)kr;
    short8_t kA1 = *(const short8_t*)(kr + 32);
    #pragma unroll
    for (int hh = 0; hh < 2; ++hh) {
      f32x4 c0 = __builtin_amdgcn_mfma_f32_16x16x32_bf16(kA0, qB[hh][0], fz, 0, 0, 0);
      sp[hh][ct] = __builtin_amdgcn_mfma_f32_16x16x32_bf16(kA1, qB[hh][1], c0, 0, 0, 0);
    }
  }

  short4_t pB[2][8];
  #pragma unroll
  for (int hh = 0; hh < 2; ++hh) {
    float mx = -INFINITY;
    #pragma unroll
    for (int ct = 0; ct < 8; ++ct)
      #pragma unroll
      for (int r = 0; r < 4; ++r) {
        int c = ct * 16 + quad * 4 + r;
        float s_ = (c <= cmaxv) ? sp[hh][ct][r] : -INFINITY;
        sp[hh][ct][r] = s_;
        mx = fmaxf(mx, s_);
      }
    mx = fmaxf(mx, __shfl_xor(mx, 16));
    mx = fmaxf(mx, __shfl_xor(mx, 32));
    if (mx == -INFINITY) mx = 0.f;  // fully-masked rows (t < 31)
    float ls = 0.f;
    #pragma unroll
    for (int ct = 0; ct < 8; ++ct)
      #pragma unroll
      for (int r = 0; r < 4; ++r) {
        float p = __expf(sp[hh][ct][r] - mx);
        sp[hh][ct][r] = p;
        ls += p;
      }
    ls += __shfl_xor(ls, 16);
    ls += __shfl_xor(ls, 32);
    float inv = (ls > 0.f) ? 1.f / ls : 0.f;
    #pragma unroll
    for (int ct = 0; ct < 8; ++ct) {
      short4_t pk;
      #pragma unroll
      for (int r = 0; r < 4; ++r) {
        float pn = sp[hh][ct][r] * inv;
        sp[hh][ct][r] = pn;
        pk[r] = (short)f2bf(pn);
      }
      pB[hh][ct] = pk;
    }
  }

  #pragma unroll
  for (int ct = 0; ct < 8; ++ct)
    #pragma unroll
    for (int r = 0; r < 4; ++r)
      atomicAdd(&colsum[l16][ct * 16 + quad * 4 + r],
                sp[0][ct][r] + sp[1][ct][r]);

  f32x4 acc[2][4];
  #pragma unroll
  for (int hh = 0; hh < 2; ++hh)
    #pragma unroll
    for (int dt = 0; dt < 4; ++dt) acc[hh][dt] = fz;
  #pragma unroll
  for (int ct = 0; ct < 8; ++ct) {
    short4_t vA[4];
    #pragma unroll
    for (int dt = 0; dt < 4; ++dt)
      vA[dt] = *(const short4_t*)(cvt16 +
          ((size_t)g * HD + dt * 16 + l16) * 128 + ct * 16 + quad * 4);
    #pragma unroll
    for (int hh = 0; hh < 2; ++hh)
      #pragma unroll
      for (int dt = 0; dt < 4; ++dt)
        acc[hh][dt] = __builtin_amdgcn_mfma_f32_16x16x16bf16_1k(
            vA[dt], pB[hh][ct], acc[hh][dt], 0, 0, 0);
  }

  const float g0 = 1.f / (1.f + __expf(-kvg[(size_t)t * KVGW + 256]));
  #pragma unroll
  for (int hh = 0; hh < 2; ++hh)
    #pragma unroll
    for (int dt = 0; dt < 4; ++dt)
      #pragma unroll
      for (int r = 0; r < 4; ++r)
        comb[((size_t)t * NHQ + g * 16 + h0 + hh) * HD + dt * 16 + quad * 4 + r] =
            g0 * acc[hh][dt][r];

  __syncthreads();

  {
    const int tl = tid >> 5;   // 0..15
    const int b = tid & 31;
    float s;
    if (b > qb) s = -INFINITY;
    else if (b == 0 || qb - b < 2) s = INFINITY;
    else {
      s = 0.f;
      #pragma unroll
      for (int i = 0; i < 5; ++i) s += colsum[tl][4 * b - 1 + i];
    }
    unsigned key = (s < 0.f) ? 0u : (__float_as_uint(s) + 1u);
    unsigned msel = 0;
    for (int it = 0; it < 16; ++it) {
      unsigned long long pk =
          (((unsigned long long)key) << 6) | (unsigned)(63 - b);
      #pragma unroll
      for (int off = 16; off >= 1; off >>= 1) {
        unsigned long long o = __shfl_xor(pk, off);
        if (o > pk) pk = o;
      }
      if ((pk >> 6) == 0) break;  // uniform within the 32-group
      int bs = 63 - (int)(pk & 63);
      msel |= 1u << bs;
      if (b == bs) key = 0;
    }
    if (b == 0) sel[(size_t)(t0 + tl) * NG + g] = msel;
  }
}

// ------- MFMA flash attention v6: 512 thr = 8 waves = 2 heads x 4 q-tiles,
// K/V LDS tiles staged ONCE per key-block and shared by both heads (halves
// staging traffic + wg count vs v5). Wave w: head hgp*2+(w>>2), queries
// t0+(w&3)*16..+15. Double-buffered 2-phase (STAGE next | compute cur |
// one barrier). q pre-scaled 1/8 -> mask = single cndmask. p->bf16 via
// v_cvt_pk_bf16_f32 (T12). Row-sum l via ones-row MFMA (no VALU adds).
// V staging/read perm (row&7)^((row>>3)&1) kills the 4-way b64 conflict.
// grid (32 qb, 2 g, 16 = 8 hgp x 2 mode). (512,2): 128-VGPR cap, no spill
// (proven config; (*,4) caps at 64 VGPR and spills ~1GB — round-3).
__global__ __launch_bounds__(512, 2) void mfma_attn(
    const ushort* __restrict__ qb16, const ushort* __restrict__ kb16,
    const ushort* __restrict__ vtb, const float* __restrict__ kvg,
    const unsigned* __restrict__ sel, float* __restrict__ comb1,
    float* __restrict__ comb2) {
  const int qb = blockIdx.x, g = blockIdx.y;
  const int hgp = blockIdx.z & 7, mode = blockIdx.z >> 3;
  const int tid = threadIdx.x, lane = tid & 63, w = tid >> 6;  // 8 waves
  const int quad = lane >> 4, l16 = lane & 15;
  const int head = g * 16 + hgp * 2 + (w >> 2);
  const int t0 = qb * 64;

  __shared__ __align__(16) ushort Ks[2][64 * 64];  // 16 KB (dbuf)
  __shared__ __align__(16) ushort Vs[2][64 * 64];  // 16 KB (dbuf)
  __shared__ unsigned sel_s[64];

  if (tid < 64) sel_s[tid] = sel[(size_t)(t0 + tid) * NG + g];
  __syncthreads();

  // my 16 queries (one 16-row tile per wave)
  const int qg = t0 + (w & 3) * 16 + l16;
  const unsigned sbq = sel_s[(w & 3) * 16 + l16];

  short8_t qB0 = *(const short8_t*)(qb16 +
      ((size_t)qg * NHQ + head) * HD + quad * 8);
  short8_t qB1 = *(const short8_t*)(qb16 +
      ((size_t)qg * NHQ + head) * HD + 32 + quad * 8);

  float m_ = -1e30f;
  f32x4 acc[4], accL;
  const f32x4 fz = {0.f, 0.f, 0.f, 0.f};
  #pragma unroll
  for (int dt = 0; dt < 4; ++dt) acc[dt] = fz;
  accL = fz;
  const short4_t onesA = {(short)0x3F80, (short)0x3F80,
                          (short)0x3F80, (short)0x3F80};  // bf16 1.0 x4

  // full key-block list (same for all 8 waves)
  unsigned mrem = 0; int b0 = 0, nb = 0;
  if (mode == 0) {
    unsigned uni = sel_s[lane];  // wave-parallel union OR-reduce
    #pragma unroll
    for (int off = 32; off >= 1; off >>= 1) uni |= __shfl_xor(uni, off);
    mrem = uni;
    nb = __popc(mrem);
  } else {
    b0 = (qb > 8) ? qb - 8 : 0;
    nb = qb - b0 + 1;
  }

  // stage K (64 keys x 64 dims) and V^T (64 dims x 64 keys) into LDS:
  // 1 K-chunk + 1 V-chunk (16B) per thread, coalesced glds16; source chunk
  // XOR-permuted (inverse swizzle) so swizzled reads are bank-clean (rule 21).
  #define STAGE(buf, blk)                                                     \
    {                                                                         \
      const int blk_ = (blk);                                                 \
      const int row = tid >> 3, cl = tid & 7;                                 \
      const int kck = cl ^ (row & 7);                                         \
      const int kcv = cl ^ ((row & 7) ^ ((row >> 3) & 1));                    \
      glds16(kb16 + (size_t)(blk_ * 64 + row) * 128 + g * 64 + kck * 8,       \
             &Ks[buf][tid * 8]);                                              \
      glds16(vtb + ((size_t)g * 64 + row) * 2048 + blk_ * 64 + kcv * 8,       \
             &Vs[buf][tid * 8]);                                              \
    }

  int blkcur;
  if (mode == 0) { blkcur = __ffs(mrem) - 1; mrem &= mrem - 1; }
  else blkcur = b0;
  STAGE(0, blkcur);
  __syncthreads();  // drains vmcnt(0): tile 0 resident

  const int e = l16 & 7;                 // K-read perm (rows = 0 mod 16)
  const int pv = e ^ ((l16 >> 3) & 1);   // V-read perm (bit3 declashes banks)

  for (int ib = 0; ib < nb; ++ib) {
    const int cur = ib & 1;
    const int blk = blkcur;
    if (ib + 1 < nb) {  // prefetch next tile into other buffer
      if (mode == 0) { blkcur = __ffs(mrem) - 1; mrem &= mrem - 1; }
      else blkcur = b0 + ib + 1;
      STAGE(cur ^ 1, blkcur);
    }

    // S^T = K Q^T from LDS (swizzled reads; 16B aligned)
    f32x4 sp[4];
    __builtin_amdgcn_s_setprio(1);
    #pragma unroll
    for (int kt = 0; kt < 4; ++kt) {
      const ushort* kr = &Ks[cur][(kt * 16 + l16) * 64];
      short8_t kA0 = *(const short8_t*)(kr + ((quad ^ e) * 8));
      short8_t kA1 = *(const short8_t*)(kr + ((quad ^ e ^ 4) * 8));
      f32x4 c = __builtin_amdgcn_mfma_f32_16x16x32_bf16(kA0, qB0, fz, 0, 0, 0);
      sp[kt] = __builtin_amdgcn_mfma_f32_16x16x32_bf16(kA1, qB1, c, 0, 0, 0);
    }
    __builtin_amdgcn_s_setprio(0);

    const bool diag = (blk == qb);                     // causal mask needed
    const bool wedge = (mode == 1) && (blk == qb - 8); // window-edge mask
    const bool selq = (mode != 0) || (((sbq >> blk) & 1u) != 0);

    float mx = -INFINITY;
    if (!diag && !wedge) {
      // whole 64-key block valid iff selq (uniform across this query's keys)
      #pragma unroll
      for (int kt = 0; kt < 4; ++kt)
        #pragma unroll
        for (int r = 0; r < 4; ++r) {
          float s_ = selq ? sp[kt][r] : -INFINITY;  // q pre-scaled: no mul
          sp[kt][r] = s_;
          mx = fmaxf(mx, s_);
        }
    } else {
      #pragma unroll
      for (int kt = 0; kt < 4; ++kt)
        #pragma unroll
        for (int r = 0; r < 4; ++r) {
          int key = blk * 64 + kt * 16 + quad * 4 + r;
          bool ok = selq && (key <= qg) && (qg - key <= 512);
          float s_ = ok ? sp[kt][r] : -INFINITY;
          sp[kt][r] = s_;
          mx = fmaxf(mx, s_);
        }
    }
    mx = fmaxf(mx, __shfl_xor(mx, 16));
    mx = fmaxf(mx, __shfl_xor(mx, 32));
    float mold = m_;
    if (!__all(mx <= mold + 8.f)) {  // T13 defer-max: rescale rarely
      float mnew = fmaxf(mold, mx);
      float alpha = __expf(mold - mnew);
      #pragma unroll
      for (int dt = 0; dt < 4; ++dt)
        #pragma unroll
        for (int r = 0; r < 4; ++r) acc[dt][r] *= alpha;
      #pragma unroll
      for (int r = 0; r < 4; ++r) accL[r] *= alpha;
      m_ = mnew;
      mold = mnew;
    }
    short4_t pB[4];
    #pragma unroll
    for (int kt = 0; kt < 4; ++kt) {
      float p0 = __expf(sp[kt][0] - mold);  // exp(-inf)=0; p <= e^8
      float p1 = __expf(sp[kt][1] - mold);
      float p2 = __expf(sp[kt][2] - mold);
      float p3 = __expf(sp[kt][3] - mold);
      union { unsigned u[2]; short4_t s; } pk;
      asm("v_cvt_pk_bf16_f32 %0, %1, %2" : "=v"(pk.u[0]) : "v"(p0), "v"(p1));
      asm("v_cvt_pk_bf16_f32 %0, %1, %2" : "=v"(pk.u[1]) : "v"(p2), "v"(p3));
      pB[kt] = pk.s;
    }

    // O^T += V^T P^T from LDS; l-sum via ones-row MFMA (all lanes get total)
    __builtin_amdgcn_s_setprio(1);
    #pragma unroll
    for (int kt = 0; kt < 4; ++kt) {
      const int sc = kt * 2 + (quad >> 1);  // source 16B chunk of this 8B read
      #pragma unroll
      for (int dt = 0; dt < 4; ++dt) {
        short4_t vA = *(const short4_t*)(&Vs[cur][(dt * 16 + l16) * 64 +
                                                  ((sc ^ pv) * 8) + (quad & 1) * 4]);
        acc[dt] = __builtin_amdgcn_mfma_f32_16x16x16bf16_1k(
            vA, pB[kt], acc[dt], 0, 0, 0);
      }
      accL = __builtin_amdgcn_mfma_f32_16x16x16bf16_1k(
          onesA, pB[kt], accL, 0, 0, 0);
    }
    __builtin_amdgcn_s_setprio(0);

    __syncthreads();  // all reads of buf[cur] done; next STAGE may overwrite
  }
  #undef STAGE

  // epilogue: each wave owns its 16 queries — no merge needed
  const float l_ = accL[0];
  const float c_ =
      (1.f / (1.f + __expf(-kvg[(size_t)qg * KVGW + 257 + mode]))) / l_;
  #pragma unroll
  for (int dt = 0; dt < 4; ++dt)
    #pragma unroll
    for (int r = 0; r < 4; ++r) {
      const int d = dt * 16 + quad * 4 + r;
      size_t idx = ((size_t)qg * NHQ + head) * HD + d;
      if (mode == 0) comb1[idx] += c_ * acc[dt][r];
      else           comb2[idx]  = c_ * acc[dt][r];
    }
}

extern "C" void kernel_launch(void* const* d_in, const int* in_sizes, int n_in,
                              void* d_out, int out_size, void* d_ws, size_t ws_size,
                              hipStream_t stream) {
  const float* x   = (const float*)d_in[0];
  const float* Wq  = (const float*)d_in[1];
  const float* Wk  = (const float*)d_in[2];
  const float* Wv  = (const float*)d_in[3];
  const float* Wo  = (const float*)d_in[4];
  const float* Wg  = (const float*)d_in[5];
  const float* Wck = (const float*)d_in[6];
  const float* Wcv = (const float*)d_in[7];
  float* out = (float*)d_out;
  float* ws = (float*)d_ws;

  float* qbuf   = ws;                           // 4,194,304 f
  float* comb1  = qbuf + 4194304;               // 4,194,304 f
  float* kvg    = comb1 + 4194304;              //   786,432 f
  float* ckb    = kvg + 786432;                 //    16,384 f (bf16 ck+cvT)
  float* cvb    = ckb + 16384;                  //    16,384 f (unused)
  unsigned* sel = (unsigned*)(cvb + 16384);     //     4,096 u32
  ushort* kbf   = (ushort*)(sel + 4096);        //   262,144 u16
  ushort* vtb   = kbf + 262144;                 //   262,144 u16
  ushort* wkvgb = vtb + 262144;                 //   786,432 u16
  ushort* regA  = wkvgb + 786432;               // 4,194,304 u16: xb -> combb
  ushort* regB  = regA + 4194304;               // 4,194,304 u16: wqb -> qbf
  ushort* xb = regA;      ushort* combb = regA;
  ushort* wqb = regB;     ushort* qbf = regB;
  float* comb2 = qbuf;                // fp32 q dead after rope_all
  ushort* wob = (ushort*)qbuf;        // written after comb2 consumed

  ushort* ckb16 = (ushort*)ckb;       // 128*2*64 u16 = 32 KB
  ushort* cvtb  = ckb16 + 16384;      // 2*64*128 u16 = 32 KB (within ckb slot)

  const int CV = (4194304 + 255) / 256;
  cvt_bf<<<CV, 256, 0, stream>>>(x, xb, 4194304);
  cvt_bf<<<CV, 256, 0, stream>>>(Wq, wqb, 4194304);
  pack_wkvg<<<(KVGW * 2048 + 255) / 256, 256, 0, stream>>>(Wk, Wv, Wg, wkvgb);

  mgemm<<<dim3(16, 16), 256, 0, stream>>>(xb, wqb, qbuf, 2048, 2048, 2048);
  mgemm<<<dim3(3, 16), 256, 0, stream>>>(xb, wkvgb, kvg, 2048, KVGW, 2048);

  rope_all<<<2048, 256, 0, stream>>>(qbuf, kvg, qbf, kbf);
  cvt_vt<<<(262144 + 255) / 256, 256, 0, stream>>>(kvg, vtb);
  compress_kv<<<dim3(128, 2), 256, 0, stream>>>(kvg, Wck, Wcv, ckb16, cvtb);
  comp_attn<<<dim3(128, 2), 512, 0, stream>>>(qbf, ckb16, cvtb, kvg, comb1, sel);
  mfma_attn<<<dim3(32, 2, 16), 512, 0, stream>>>(qbf, kbf, vtb, kvg, sel, comb1, comb2);

  cvt_sum2_bf<<<CV, 256, 0, stream>>>(comb1, comb2, combb, 4194304);
  cvt_bf<<<CV, 256, 0, stream>>>(Wo, wob, 4194304);
  mgemm<<<dim3(16, 16), 256, 0, stream>>>(combb, wob, out, 2048, 2048, 2048);
}

// Round 7
// 399.483 us; speedup vs baseline: 2.0169x; 1.0549x over previous
//
#include <hip/hip_runtime.h>
#include <math.h>

#define T_SEQ 2048
#define NHQ 32
#define NG 2
#define HD 64
#define CSTRIDE 16
#define KVGW 384  // fused k|v|gate row width: 128 k + 128 v + 3 gate + pad

typedef __attribute__((ext_vector_type(8))) short short8_t;
typedef __attribute__((ext_vector_type(4))) short short4_t;
typedef __attribute__((ext_vector_type(4))) float f32x4;

__device__ __forceinline__ ushort f2bf(float x) {  // round-to-nearest-even
  union { float f; unsigned u; } c; c.f = x;
  unsigned r = c.u + 0x7fff + ((c.u >> 16) & 1);
  return (ushort)(r >> 16);
}
__device__ __forceinline__ float bf2f(ushort u) {
  union { unsigned u; float f; } c; c.u = ((unsigned)u) << 16;
  return c.f;
}

__device__ __forceinline__ void glds16(const ushort* g, ushort* l) {
  __builtin_amdgcn_global_load_lds(
      (const __attribute__((address_space(1))) unsigned int*)g,
      (__attribute__((address_space(3))) unsigned int*)l, 16, 0, 0);
}

// ---- bf16 MFMA GEMM: C[M,N] = A[M,K] * B[N,K]^T (m97 recipe + XOR swizzle)
// 512 thr = 8 waves, wave tile 64x32 (vs 4-wave 64x64): at N=2048 the grid
// is 256 wgs = 1 wg/CU, so 8 waves/CU (vs 4) doubles latency hiding with
// identical tiles/traffic/swizzle.
__global__ __launch_bounds__(512) void mgemm(
    const ushort* __restrict__ A, const ushort* __restrict__ B,
    float* __restrict__ C, int M, int N, int K) {
  __shared__ __align__(16) ushort As[128 * 64];
  __shared__ __align__(16) ushort Bs[128 * 64];
  const int tid = threadIdx.x;
  const int lane = tid & 63, w = tid >> 6;  // 8 waves
  const int quad = lane >> 4, l16 = lane & 15;
  const int m0 = blockIdx.y * 128, n0 = blockIdx.x * 128;
  const int mq = (w & 1) * 64, nq = (w >> 1) * 32;
  f32x4 acc[4][2];
  const f32x4 fz = {0.f, 0.f, 0.f, 0.f};
  #pragma unroll
  for (int i = 0; i < 4; ++i)
    #pragma unroll
    for (int j = 0; j < 2; ++j) acc[i][j] = fz;

  for (int k0 = 0; k0 < K; k0 += 64) {
    __syncthreads();
    #pragma unroll
    for (int j = 0; j < 2; ++j) {
      int ci = j * 512 + tid;
      int row = ci >> 3, cl = ci & 7;
      int kc = cl ^ (row & 7);
      glds16(A + ((size_t)(m0 + row) * K + k0 + kc * 8), &As[ci * 8]);
      glds16(B + ((size_t)(n0 + row) * K + k0 + kc * 8), &Bs[ci * 8]);
    }
    __syncthreads();
    #pragma unroll
    for (int kt = 0; kt < 2; ++kt) {
      short8_t af[4], bf_[2];
      #pragma unroll
      for (int mt = 0; mt < 4; ++mt) {
        int row = mq + mt * 16 + l16;
        int cl = (kt * 4 + quad) ^ (row & 7);
        af[mt] = *(const short8_t*)&As[row * 64 + cl * 8];
      }
      #pragma unroll
      for (int nt = 0; nt < 2; ++nt) {
        int row = nq + nt * 16 + l16;
        int cl = (kt * 4 + quad) ^ (row & 7);
        bf_[nt] = *(const short8_t*)&Bs[row * 64 + cl * 8];
      }
      #pragma unroll
      for (int mt = 0; mt < 4; ++mt)
        #pragma unroll
        for (int nt = 0; nt < 2; ++nt)
          acc[mt][nt] = __builtin_amdgcn_mfma_f32_16x16x32_bf16(
              af[mt], bf_[nt], acc[mt][nt], 0, 0, 0);
    }
  }
  #pragma unroll
  for (int mt = 0; mt < 4; ++mt)
    #pragma unroll
    for (int nt = 0; nt < 2; ++nt)
      #pragma unroll
      for (int r = 0; r < 4; ++r) {
        int m = m0 + mq + mt * 16 + quad * 4 + r;
        int n = n0 + nq + nt * 16 + l16;
        C[(size_t)m * N + n] = acc[mt][nt][r];
      }
}

// ---------------- conversions / packing ----------------
__global__ __launch_bounds__(256) void cvt_bf(const float* __restrict__ src,
                                              ushort* __restrict__ dst, int n) {
  int i = blockIdx.x * 256 + threadIdx.x;
  if (i < n) dst[i] = f2bf(src[i]);
}

__global__ __launch_bounds__(256) void cvt_sum2_bf(const float* __restrict__ a,
                                                   const float* __restrict__ b,
                                                   ushort* __restrict__ dst, int n) {
  int i = blockIdx.x * 256 + threadIdx.x;
  if (i < n) dst[i] = f2bf(a[i] + b[i]);
}

__global__ __launch_bounds__(256) void pack_wkvg(
    const float* __restrict__ Wk, const float* __restrict__ Wv,
    const float* __restrict__ Wg, ushort* __restrict__ dst) {
  int i = blockIdx.x * 256 + threadIdx.x;
  if (i >= KVGW * 2048) return;
  int n = i >> 11, k = i & 2047;
  float v;
  if (n < 128) v = Wk[(size_t)n * 2048 + k];
  else if (n < 256) v = Wv[(size_t)(n - 128) * 2048 + k];
  else if (n < 259) v = Wg[(size_t)(n - 256) * 2048 + k];
  else v = 0.f;
  dst[i] = f2bf(v);
}

// vt[g][d][*] bf16 from kvg v-part (v is NOT roped), with an 8B-slot
// permutation baked into each 64-key block: key k of block blk is stored at
// blk*64 + ((k>>2)^(d&15))*4 + (k&3). mfma_attn stages rows LINEARLY and
// reads slot (kt*4+quad)^l16 -> 16 distinct slots per 16-lane LDS phase =
// bank-conflict-free b64 reads (the 16B-granular staging swizzle provably
// cannot fix this: slot parity was pinned by quad&1 -> 2-way on every read,
// the 6.39M-conflict constant of rounds 5/6).
__global__ __launch_bounds__(256) void cvt_vt(const float* __restrict__ kvg,
                                              ushort* __restrict__ vt) {
  int i = blockIdx.x * 256 + threadIdx.x;
  if (i >= T_SEQ * NG * HD) return;
  int d = i & 63, g = (i >> 6) & 1, s = i >> 7;
  int blk = s >> 6, k = s & 63;
  int snew = blk * 64 + (((k >> 2) ^ (d & 15)) << 2) + (k & 3);
  vt[((size_t)g * HD + d) * T_SEQ + snew] =
      f2bf(kvg[(size_t)s * KVGW + 128 + g * 64 + d]);
}

// ------- RoPE: q fp32 -> qbf bf16 PRE-SCALED by 1/8 (exact exponent shift,
// lossless in bf16; lets attention kernels drop the per-score SCALE mul).
// kvg k-part roped in place + kbf bf16 (NOT scaled).
__global__ __launch_bounds__(256) void rope_all(
    const float* __restrict__ q, float* __restrict__ kvg,
    ushort* __restrict__ qbf, ushort* __restrict__ kbf) {
  const int t = blockIdx.x;
  const float lnb_over = 9.210340371976184f / 32.f;  // ln(10000)/32
  for (int job = threadIdx.x; job < (NHQ + NG) * 32; job += 256) {
    int h = job >> 5, j = job & 31;
    float inv = expf(-(float)j * lnb_over);
    float fr = (float)t * inv;
    float c_ = cosf(fr), s_ = sinf(fr);
    if (h < NHQ) {
      const float cq = c_ * 0.125f, sq = s_ * 0.125f;
      const float* base = q + ((size_t)t * NHQ + h) * HD;
      float x1 = base[j], x2 = base[j + 32];
      ushort* ob = qbf + ((size_t)t * NHQ + h) * HD;
      ob[j] = f2bf(x1 * cq - x2 * sq);
      ob[j + 32] = f2bf(x2 * cq + x1 * sq);
    } else {
      int g = h - NHQ;
      float* base = kvg + (size_t)t * KVGW + g * 64;
      float x1 = base[j], x2 = base[j + 32];
      float o1 = x1 * c_ - x2 * s_, o2 = x2 * c_ + x1 * s_;
      base[j] = o1; base[j + 32] = o2;
      kbf[(size_t)t * 128 + g * 64 + j] = f2bf(o1);
      kbf[(size_t)t * 128 + g * 64 + j + 32] = f2bf(o2);
    }
  }
}

// ------- compression: bf16 ck[c][g][d] and transposed bf16 cv^T[g][d][c] ---
// grid (128, 2); c==127 writes the zero pad row (c is padded 127 -> 128).
__global__ __launch_bounds__(256) void compress_kv(
    const float* __restrict__ kvg,
    const float* __restrict__ Wck, const float* __restrict__ Wcv,
    ushort* __restrict__ ck16, ushort* __restrict__ cvt16) {
  const int c = blockIdx.x, g = blockIdx.y;
  const int tid = threadIdx.x;
  if (c == 127) {  // zero pad so MFMA never touches garbage
    if (tid < 64) ck16[((size_t)127 * NG + g) * HD + tid] = 0;
    else if (tid < 128) cvt16[((size_t)g * HD + (tid - 64)) * 128 + 127] = 0;
    return;
  }
  const int d = tid & 63, chunk = tid >> 6;
  __shared__ float red[2][4][64];
  float ak = 0.f, av = 0.f;
  for (int f = chunk * 512; f < chunk * 512 + 512; ++f) {
    int i = f >> 6, e = f & 63;
    int trow = c * CSTRIDE + i;
    float kv = kvg[(size_t)trow * KVGW + g * 64 + e];
    float vv = kvg[(size_t)trow * KVGW + 128 + g * 64 + e];
    ak += kv * Wck[((size_t)g * 2048 + f) * HD + d];
    av += vv * Wcv[((size_t)g * 2048 + f) * HD + d];
  }
  red[0][chunk][d] = ak;
  red[1][chunk][d] = av;
  __syncthreads();
  if (tid < 64) {
    ck16[((size_t)c * NG + g) * HD + tid] =
        f2bf(red[0][0][tid] + red[0][1][tid] + red[0][2][tid] + red[0][3][tid]);
  } else if (tid < 128) {
    int dd = tid - 64;
    cvt16[((size_t)g * HD + dd) * 128 + c] =
        f2bf(red[1][0][dd] + red[1][1][dd] + red[1][2][dd] + red[1][3][dd]);
  }
}

// ------- MFMA compressed attention + block scores + parallel top-16 -------
// grid (128 t-tiles of 16, 2 g), 512 threads = 8 waves x 2 heads each.
// q is pre-scaled by 1/8 (rope_all), so scores need no SCALE mul.
__global__ __launch_bounds__(512) void comp_attn(
    const ushort* __restrict__ qbf, const ushort* __restrict__ ck16,
    const ushort* __restrict__ cvt16, const float* __restrict__ kvg,
    float* __restrict__ comb, unsigned* __restrict__ sel) {
  const int tb = blockIdx.x, g = blockIdx.y;
  const int t0 = tb * 16;
  const int tid = threadIdx.x, lane = tid & 63, w = tid >> 6;
  const int quad = lane >> 4, l16 = lane & 15;
  const int qb = t0 >> 6;  // uniform across the 16 t's of this block

  __shared__ float colsum[16][129];  // [t_local][c], padded vs bank conflicts
  for (int i = tid; i < 16 * 129; i += 512) ((float*)colsum)[i] = 0.f;
  __syncthreads();

  const int t = t0 + l16;
  const int cmaxv = (t >= 31) ? min(126, (t - 31) >> 4) : -1;
  const int h0 = w * 2;  // two heads per wave

  short8_t qB[2][2];
  #pragma unroll
  for (int hh = 0; hh < 2; ++hh)
    #pragma unroll
    for (int kd = 0; kd < 2; ++kd)
      qB[hh][kd] = *(const short8_t*)(qbf +
          ((size_t)t * NHQ + g * 16 + h0 + hh) * HD + kd * 32 + quad * 8);

  const f32x4 fz = {0.f, 0.f, 0.f, 0.f};
  f32x4 sp[2][8];

  #pragma unroll
  for (int ct = 0; ct < 8; ++ct) {
    const ushort* kr = ck16 + ((size_t)(ct * 16 + l16) * NG + g) * HD + quad * 8;
    short8_t kA0 = *(const short8_t*)kr;
    short8_t kA1 = *(const short8_t*)(kr + 32);
    #pragma unroll
    for (int hh = 0; hh < 2; ++hh) {
      f32x4 c0 = __builtin_amdgcn_mfma_f32_16x16x32_bf16(kA0, qB[hh][0], fz, 0, 0, 0);
      sp[hh][ct] = __builtin_amdgcn_mfma_f32_16x16x32_bf16(kA1, qB[hh][1], c0, 0, 0, 0);
    }
  }

  short4_t pB[2][8];
  #pragma unroll
  for (int hh = 0; hh < 2; ++hh) {
    float mx = -INFINITY;
    #pragma unroll
    for (int ct = 0; ct < 8; ++ct)
      #pragma unroll
      for (int r = 0; r < 4; ++r) {
        int c = ct * 16 + quad * 4 + r;
        float s_ = (c <= cmaxv) ? sp[hh][ct][r] : -INFINITY;
        sp[hh][ct][r] = s_;
        mx = fmaxf(mx, s_);
      }
    mx = fmaxf(mx, __shfl_xor(mx, 16));
    mx = fmaxf(mx, __shfl_xor(mx, 32));
    if (mx == -INFINITY) mx = 0.f;  // fully-masked rows (t < 31)
    float ls = 0.f;
    #pragma unroll
    for (int ct = 0; ct < 8; ++ct)
      #pragma unroll
      for (int r = 0; r < 4; ++r) {
        float p = __expf(sp[hh][ct][r] - mx);
        sp[hh][ct][r] = p;
        ls += p;
      }
    ls += __shfl_xor(ls, 16);
    ls += __shfl_xor(ls, 32);
    float inv = (ls > 0.f) ? 1.f / ls : 0.f;
    #pragma unroll
    for (int ct = 0; ct < 8; ++ct) {
      short4_t pk;
      #pragma unroll
      for (int r = 0; r < 4; ++r) {
        float pn = sp[hh][ct][r] * inv;
        sp[hh][ct][r] = pn;
        pk[r] = (short)f2bf(pn);
      }
      pB[hh][ct] = pk;
    }
  }

  #pragma unroll
  for (int ct = 0; ct < 8; ++ct)
    #pragma unroll
    for (int r = 0; r < 4; ++r)
      atomicAdd(&colsum[l16][ct * 16 + quad * 4 + r],
                sp[0][ct][r] + sp[1][ct][r]);

  f32x4 acc[2][4];
  #pragma unroll
  for (int hh = 0; hh < 2; ++hh)
    #pragma unroll
    for (int dt = 0; dt < 4; ++dt) acc[hh][dt] = fz;
  #pragma unroll
  for (int ct = 0; ct < 8; ++ct) {
    short4_t vA[4];
    #pragma unroll
    for (int dt = 0; dt < 4; ++dt)
      vA[dt] = *(const short4_t*)(cvt16 +
          ((size_t)g * HD + dt * 16 + l16) * 128 + ct * 16 + quad * 4);
    #pragma unroll
    for (int hh = 0; hh < 2; ++hh)
      #pragma unroll
      for (int dt = 0; dt < 4; ++dt)
        acc[hh][dt] = __builtin_amdgcn_mfma_f32_16x16x16bf16_1k(
            vA[dt], pB[hh][ct], acc[hh][dt], 0, 0, 0);
  }

  const float g0 = 1.f / (1.f + __expf(-kvg[(size_t)t * KVGW + 256]));
  #pragma unroll
  for (int hh = 0; hh < 2; ++hh)
    #pragma unroll
    for (int dt = 0; dt < 4; ++dt)
      #pragma unroll
      for (int r = 0; r < 4; ++r)
        comb[((size_t)t * NHQ + g * 16 + h0 + hh) * HD + dt * 16 + quad * 4 + r] =
            g0 * acc[hh][dt][r];

  __syncthreads();

  {
    const int tl = tid >> 5;   // 0..15
    const int b = tid & 31;
    float s;
    if (b > qb) s = -INFINITY;
    else if (b == 0 || qb - b < 2) s = INFINITY;
    else {
      s = 0.f;
      #pragma unroll
      for (int i = 0; i < 5; ++i) s += colsum[tl][4 * b - 1 + i];
    }
    unsigned key = (s < 0.f) ? 0u : (__float_as_uint(s) + 1u);
    unsigned msel = 0;
    for (int it = 0; it < 16; ++it) {
      unsigned long long pk =
          (((unsigned long long)key) << 6) | (unsigned)(63 - b);
      #pragma unroll
      for (int off = 16; off >= 1; off >>= 1) {
        unsigned long long o = __shfl_xor(pk, off);
        if (o > pk) pk = o;
      }
      if ((pk >> 6) == 0) break;  // uniform within the 32-group
      int bs = 63 - (int)(pk & 63);
      msel |= 1u << bs;
      if (b == bs) key = 0;
    }
    if (b == 0) sel[(size_t)(t0 + tl) * NG + g] = msel;
  }
}

// ------- MFMA flash attention v7: 512 thr = 8 waves = 2 heads x 4 q-tiles,
// K/V LDS tiles staged once per key-block, shared by both heads. Wave w:
// head hgp*2+(w>>2), queries t0+(w&3)*16..+15. Double-buffered 2-phase.
// q pre-scaled 1/8. p->bf16 via v_cvt_pk_bf16_f32. l via ones-row MFMA.
// K: 16B XOR chunk swizzle (conflict-free: 8-lane phases hit 8 groups).
// V: 8B-slot perm pre-baked in vtb (see cvt_vt) -> linear staging, read
// slot (kt*4+quad)^l16 -> conflict-free b64 phases.
// grid (32 qb, 2 g, 16 = 8 hgp x 2 mode). (512,2): 128-VGPR cap, no spill.
__global__ __launch_bounds__(512, 2) void mfma_attn(
    const ushort* __restrict__ qb16, const ushort* __restrict__ kb16,
    const ushort* __restrict__ vtb, const float* __restrict__ kvg,
    const unsigned* __restrict__ sel, float* __restrict__ comb1,
    float* __restrict__ comb2) {
  const int qb = blockIdx.x, g = blockIdx.y;
  const int hgp = blockIdx.z & 7, mode = blockIdx.z >> 3;
  const int tid = threadIdx.x, lane = tid & 63, w = tid >> 6;  // 8 waves
  const int quad = lane >> 4, l16 = lane & 15;
  const int head = g * 16 + hgp * 2 + (w >> 2);
  const int t0 = qb * 64;

  __shared__ __align__(16) ushort Ks[2][64 * 64];  // 16 KB (dbuf)
  __shared__ __align__(16) ushort Vs[2][64 * 64];  // 16 KB (dbuf)
  __shared__ unsigned sel_s[64];

  if (tid < 64) sel_s[tid] = sel[(size_t)(t0 + tid) * NG + g];
  __syncthreads();

  // my 16 queries (one 16-row tile per wave)
  const int qg = t0 + (w & 3) * 16 + l16;
  const unsigned sbq = sel_s[(w & 3) * 16 + l16];

  short8_t qB0 = *(const short8_t*)(qb16 +
      ((size_t)qg * NHQ + head) * HD + quad * 8);
  short8_t qB1 = *(const short8_t*)(qb16 +
      ((size_t)qg * NHQ + head) * HD + 32 + quad * 8);

  float m_ = -1e30f;
  f32x4 acc[4], accL;
  const f32x4 fz = {0.f, 0.f, 0.f, 0.f};
  #pragma unroll
  for (int dt = 0; dt < 4; ++dt) acc[dt] = fz;
  accL = fz;
  const short4_t onesA = {(short)0x3F80, (short)0x3F80,
                          (short)0x3F80, (short)0x3F80};  // bf16 1.0 x4

  // full key-block list (same for all 8 waves)
  unsigned mrem = 0; int b0 = 0, nb = 0;
  if (mode == 0) {
    unsigned uni = sel_s[lane];  // wave-parallel union OR-reduce
    #pragma unroll
    for (int off = 32; off >= 1; off >>= 1) uni |= __shfl_xor(uni, off);
    mrem = uni;
    nb = __popc(mrem);
  } else {
    b0 = (qb > 8) ? qb - 8 : 0;
    nb = qb - b0 + 1;
  }

  // stage K (XOR 16B chunk swizzle) and V^T (LINEAR — perm is pre-baked in
  // vtb's global layout) into LDS: 1 K-chunk + 1 V-chunk (16B) per thread.
  #define STAGE(buf, blk)                                                     \
    {                                                                         \
      const int blk_ = (blk);                                                 \
      const int row = tid >> 3, cl = tid & 7;                                 \
      const int kck = cl ^ (row & 7);                                         \
      glds16(kb16 + (size_t)(blk_ * 64 + row) * 128 + g * 64 + kck * 8,       \
             &Ks[buf][tid * 8]);                                              \
      glds16(vtb + ((size_t)g * 64 + row) * 2048 + blk_ * 64 + cl * 8,        \
             &Vs[buf][tid * 8]);                                              \
    }

  int blkcur;
  if (mode == 0) { blkcur = __ffs(mrem) - 1; mrem &= mrem - 1; }
  else blkcur = b0;
  STAGE(0, blkcur);
  __syncthreads();  // drains vmcnt(0): tile 0 resident

  const int e = l16 & 7;  // K-read perm (rows = 0 mod 16)

  for (int ib = 0; ib < nb; ++ib) {
    const int cur = ib & 1;
    const int blk = blkcur;
    if (ib + 1 < nb) {  // prefetch next tile into other buffer
      if (mode == 0) { blkcur = __ffs(mrem) - 1; mrem &= mrem - 1; }
      else blkcur = b0 + ib + 1;
      STAGE(cur ^ 1, blkcur);
    }

    // S^T = K Q^T from LDS (swizzled reads; 16B aligned)
    f32x4 sp[4];
    __builtin_amdgcn_s_setprio(1);
    #pragma unroll
    for (int kt = 0; kt < 4; ++kt) {
      const ushort* kr = &Ks[cur][(kt * 16 + l16) * 64];
      short8_t kA0 = *(const short8_t*)(kr + ((quad ^ e) * 8));
      short8_t kA1 = *(const short8_t*)(kr + ((quad ^ e ^ 4) * 8));
      f32x4 c = __builtin_amdgcn_mfma_f32_16x16x32_bf16(kA0, qB0, fz, 0, 0, 0);
      sp[kt] = __builtin_amdgcn_mfma_f32_16x16x32_bf16(kA1, qB1, c, 0, 0, 0);
    }
    __builtin_amdgcn_s_setprio(0);

    const bool diag = (blk == qb);                     // causal mask needed
    const bool wedge = (mode == 1) && (blk == qb - 8); // window-edge mask
    const bool selq = (mode != 0) || (((sbq >> blk) & 1u) != 0);

    float mx = -INFINITY;
    if (!diag && !wedge) {
      // whole 64-key block valid iff selq (uniform across this query's keys)
      #pragma unroll
      for (int kt = 0; kt < 4; ++kt)
        #pragma unroll
        for (int r = 0; r < 4; ++r) {
          float s_ = selq ? sp[kt][r] : -INFINITY;  // q pre-scaled: no mul
          sp[kt][r] = s_;
          mx = fmaxf(mx, s_);
        }
    } else {
      #pragma unroll
      for (int kt = 0; kt < 4; ++kt)
        #pragma unroll
        for (int r = 0; r < 4; ++r) {
          int key = blk * 64 + kt * 16 + quad * 4 + r;
          bool ok = selq && (key <= qg) && (qg - key <= 512);
          float s_ = ok ? sp[kt][r] : -INFINITY;
          sp[kt][r] = s_;
          mx = fmaxf(mx, s_);
        }
    }
    mx = fmaxf(mx, __shfl_xor(mx, 16));
    mx = fmaxf(mx, __shfl_xor(mx, 32));
    float mold = m_;
    if (!__all(mx <= mold + 8.f)) {  // T13 defer-max: rescale rarely
      float mnew = fmaxf(mold, mx);
      float alpha = __expf(mold - mnew);
      #pragma unroll
      for (int dt = 0; dt < 4; ++dt)
        #pragma unroll
        for (int r = 0; r < 4; ++r) acc[dt][r] *= alpha;
      #pragma unroll
      for (int r = 0; r < 4; ++r) accL[r] *= alpha;
      m_ = mnew;
      mold = mnew;
    }
    short4_t pB[4];
    #pragma unroll
    for (int kt = 0; kt < 4; ++kt) {
      float p0 = __expf(sp[kt][0] - mold);  // exp(-inf)=0; p <= e^8
      float p1 = __expf(sp[kt][1] - mold);
      float p2 = __expf(sp[kt][2] - mold);
      float p3 = __expf(sp[kt][3] - mold);
      union { unsigned u[2]; short4_t s; } pk;
      asm("v_cvt_pk_bf16_f32 %0, %1, %2" : "=v"(pk.u[0]) : "v"(p0), "v"(p1));
      asm("v_cvt_pk_bf16_f32 %0, %1, %2" : "=v"(pk.u[1]) : "v"(p2), "v"(p3));
      pB[kt] = pk.s;
    }

    // O^T += V^T P^T from LDS; l-sum via ones-row MFMA (all lanes get total)
    __builtin_amdgcn_s_setprio(1);
    #pragma unroll
    for (int kt = 0; kt < 4; ++kt) {
      #pragma unroll
      for (int dt = 0; dt < 4; ++dt) {
        short4_t vA = *(const short4_t*)(&Vs[cur][(dt * 16 + l16) * 64 +
                                                  (((kt * 4 + quad) ^ l16) << 2)]);
        acc[dt] = __builtin_amdgcn_mfma_f32_16x16x16bf16_1k(
            vA, pB[kt], acc[dt], 0, 0, 0);
      }
      accL = __builtin_amdgcn_mfma_f32_16x16x16bf16_1k(
          onesA, pB[kt], accL, 0, 0, 0);
    }
    __builtin_amdgcn_s_setprio(0);

    __syncthreads();  // all reads of buf[cur] done; next STAGE may overwrite
  }
  #undef STAGE

  // epilogue: each wave owns its 16 queries — no merge needed
  const float l_ = accL[0];
  const float c_ =
      (1.f / (1.f + __expf(-kvg[(size_t)qg * KVGW + 257 + mode]))) / l_;
  #pragma unroll
  for (int dt = 0; dt < 4; ++dt)
    #pragma unroll
    for (int r = 0; r < 4; ++r) {
      const int d = dt * 16 + quad * 4 + r;
      size_t idx = ((size_t)qg * NHQ + head) * HD + d;
      if (mode == 0) comb1[idx] += c_ * acc[dt][r];
      else           comb2[idx]  = c_ * acc[dt][r];
    }
}

extern "C" void kernel_launch(void* const* d_in, const int* in_sizes, int n_in,
                              void* d_out, int out_size, void* d_ws, size_t ws_size,
                              hipStream_t stream) {
  const float* x   = (const float*)d_in[0];
  const float* Wq  = (const float*)d_in[1];
  const float* Wk  = (const float*)d_in[2];
  const float* Wv  = (const float*)d_in[3];
  const float* Wo  = (const float*)d_in[4];
  const float* Wg  = (const float*)d_in[5];
  const float* Wck = (const float*)d_in[6];
  const float* Wcv = (const float*)d_in[7];
  float* out = (float*)d_out;
  float* ws = (float*)d_ws;

  float* qbuf   = ws;                           // 4,194,304 f
  float* comb1  = qbuf + 4194304;               // 4,194,304 f
  float* kvg    = comb1 + 4194304;              //   786,432 f
  float* ckb    = kvg + 786432;                 //    16,384 f (bf16 ck+cvT)
  float* cvb    = ckb + 16384;                  //    16,384 f (unused)
  unsigned* sel = (unsigned*)(cvb + 16384);     //     4,096 u32
  ushort* kbf   = (ushort*)(sel + 4096);        //   262,144 u16
  ushort* vtb   = kbf + 262144;                 //   262,144 u16
  ushort* wkvgb = vtb + 262144;                 //   786,432 u16
  ushort* regA  = wkvgb + 786432;               // 4,194,304 u16: xb -> combb
  ushort* regB  = regA + 4194304;               // 4,194,304 u16: wqb -> qbf
  ushort* xb = regA;      ushort* combb = regA;
  ushort* wqb = regB;     ushort* qbf = regB;
  float* comb2 = qbuf;                // fp32 q dead after rope_all
  ushort* wob = (ushort*)qbuf;        // written after comb2 consumed

  ushort* ckb16 = (ushort*)ckb;       // 128*2*64 u16 = 32 KB
  ushort* cvtb  = ckb16 + 16384;      // 2*64*128 u16 = 32 KB (within ckb slot)

  const int CV = (4194304 + 255) / 256;
  cvt_bf<<<CV, 256, 0, stream>>>(x, xb, 4194304);
  cvt_bf<<<CV, 256, 0, stream>>>(Wq, wqb, 4194304);
  pack_wkvg<<<(KVGW * 2048 + 255) / 256, 256, 0, stream>>>(Wk, Wv, Wg, wkvgb);

  mgemm<<<dim3(16, 16), 512, 0, stream>>>(xb, wqb, qbuf, 2048, 2048, 2048);
  mgemm<<<dim3(3, 16), 512, 0, stream>>>(xb, wkvgb, kvg, 2048, KVGW, 2048);

  rope_all<<<2048, 256, 0, stream>>>(qbuf, kvg, qbf, kbf);
  cvt_vt<<<(262144 + 255) / 256, 256, 0, stream>>>(kvg, vtb);
  compress_kv<<<dim3(128, 2), 256, 0, stream>>>(kvg, Wck, Wcv, ckb16, cvtb);
  comp_attn<<<dim3(128, 2), 512, 0, stream>>>(qbf, ckb16, cvtb, kvg, comb1, sel);
  mfma_attn<<<dim3(32, 2, 16), 512, 0, stream>>>(qbf, kbf, vtb, kvg, sel, comb1, comb2);

  cvt_sum2_bf<<<CV, 256, 0, stream>>>(comb1, comb2, combb, 4194304);
  cvt_bf<<<CV, 256, 0, stream>>>(Wo, wob, 4194304);
  mgemm<<<dim3(16, 16), 512, 0, stream>>>(combb, wob, out, 2048, 2048, 2048);
}

// Round 8
// 388.150 us; speedup vs baseline: 2.0758x; 1.0292x over previous
//
#include <hip/hip_runtime.h>
#include <math.h>

#define T_SEQ 2048
#define NHQ 32
#define NG 2
#define HD 64
#define CSTRIDE 16
#define KVGW 384  // fused k|v|gate row width: 128 k + 128 v + 3 gate + pad

typedef __attribute__((ext_vector_type(8))) short short8_t;
typedef __attribute__((ext_vector_type(4))) short short4_t;
typedef __attribute__((ext_vector_type(4))) float f32x4;

__device__ __forceinline__ ushort f2bf(float x) {  // round-to-nearest-even
  union { float f; unsigned u; } c; c.f = x;
  unsigned r = c.u + 0x7fff + ((c.u >> 16) & 1);
  return (ushort)(r >> 16);
}
__device__ __forceinline__ float bf2f(ushort u) {
  union { unsigned u; float f; } c; c.u = ((unsigned)u) << 16;
  return c.f;
}

__device__ __forceinline__ void glds16(const ushort* g, ushort* l) {
  __builtin_amdgcn_global_load_lds(
      (const __attribute__((address_space(1))) unsigned int*)g,
      (__attribute__((address_space(3))) unsigned int*)l, 16, 0, 0);
}

// ---- bf16 MFMA GEMM: C[M,N] = A[M,K] * B[N,K]^T (m97 recipe + XOR swizzle)
// v3: BM=128 x BN=64 tile, 256 thr = 4 waves (wave tile 64x32). At N=2048
// this gives grid 32x16 = 512 wgs = 2 wg/CU: two INDEPENDENT barriers per CU
// overlap each other's vmcnt drains (m114 mechanism) — the 128x128/1-wg/CU
// variant had zero cross-wg overlap. LDS 24KB x2 = 48KB, ~90 VGPR: both fit.
__global__ __launch_bounds__(256) void mgemm(
    const ushort* __restrict__ A, const ushort* __restrict__ B,
    float* __restrict__ C, int M, int N, int K) {
  __shared__ __align__(16) ushort As[128 * 64];
  __shared__ __align__(16) ushort Bs[64 * 64];
  const int tid = threadIdx.x;
  const int lane = tid & 63, w = tid >> 6;  // 4 waves
  const int quad = lane >> 4, l16 = lane & 15;
  const int m0 = blockIdx.y * 128, n0 = blockIdx.x * 64;
  const int mq = (w & 1) * 64, nq = (w >> 1) * 32;
  f32x4 acc[4][2];
  const f32x4 fz = {0.f, 0.f, 0.f, 0.f};
  #pragma unroll
  for (int i = 0; i < 4; ++i)
    #pragma unroll
    for (int j = 0; j < 2; ++j) acc[i][j] = fz;

  for (int k0 = 0; k0 < K; k0 += 64) {
    __syncthreads();
    #pragma unroll
    for (int j = 0; j < 4; ++j) {  // A: 128 rows x 8 chunks
      int ci = j * 256 + tid;
      int row = ci >> 3, cl = ci & 7;
      int kc = cl ^ (row & 7);
      glds16(A + ((size_t)(m0 + row) * K + k0 + kc * 8), &As[ci * 8]);
    }
    #pragma unroll
    for (int j = 0; j < 2; ++j) {  // B: 64 rows x 8 chunks
      int ci = j * 256 + tid;
      int row = ci >> 3, cl = ci & 7;
      int kc = cl ^ (row & 7);
      glds16(B + ((size_t)(n0 + row) * K + k0 + kc * 8), &Bs[ci * 8]);
    }
    __syncthreads();
    #pragma unroll
    for (int kt = 0; kt < 2; ++kt) {
      short8_t af[4], bf_[2];
      #pragma unroll
      for (int mt = 0; mt < 4; ++mt) {
        int row = mq + mt * 16 + l16;
        int cl = (kt * 4 + quad) ^ (row & 7);
        af[mt] = *(const short8_t*)&As[row * 64 + cl * 8];
      }
      #pragma unroll
      for (int nt = 0; nt < 2; ++nt) {
        int row = nq + nt * 16 + l16;
        int cl = (kt * 4 + quad) ^ (row & 7);
        bf_[nt] = *(const short8_t*)&Bs[row * 64 + cl * 8];
      }
      #pragma unroll
      for (int mt = 0; mt < 4; ++mt)
        #pragma unroll
        for (int nt = 0; nt < 2; ++nt)
          acc[mt][nt] = __builtin_amdgcn_mfma_f32_16x16x32_bf16(
              af[mt], bf_[nt], acc[mt][nt], 0, 0, 0);
    }
  }
  #pragma unroll
  for (int mt = 0; mt < 4; ++mt)
    #pragma unroll
    for (int nt = 0; nt < 2; ++nt)
      #pragma unroll
      for (int r = 0; r < 4; ++r) {
        int m = m0 + mq + mt * 16 + quad * 4 + r;
        int n = n0 + nq + nt * 16 + l16;
        C[(size_t)m * N + n] = acc[mt][nt][r];
      }
}

// ---------------- conversions / packing (float4-vectorized, G13) ----------
__global__ __launch_bounds__(256) void cvt_bf(const float* __restrict__ src,
                                              ushort* __restrict__ dst, int n) {
  int i = (blockIdx.x * 256 + threadIdx.x) * 4;
  if (i >= n) return;
  float4 v = *(const float4*)(src + i);
  short4_t o = {(short)f2bf(v.x), (short)f2bf(v.y),
                (short)f2bf(v.z), (short)f2bf(v.w)};
  *(short4_t*)(dst + i) = o;
}

__global__ __launch_bounds__(256) void cvt_sum2_bf(const float* __restrict__ a,
                                                   const float* __restrict__ b,
                                                   ushort* __restrict__ dst, int n) {
  int i = (blockIdx.x * 256 + threadIdx.x) * 4;
  if (i >= n) return;
  float4 va = *(const float4*)(a + i);
  float4 vb = *(const float4*)(b + i);
  short4_t o = {(short)f2bf(va.x + vb.x), (short)f2bf(va.y + vb.y),
                (short)f2bf(va.z + vb.z), (short)f2bf(va.w + vb.w)};
  *(short4_t*)(dst + i) = o;
}

__global__ __launch_bounds__(256) void pack_wkvg(
    const float* __restrict__ Wk, const float* __restrict__ Wv,
    const float* __restrict__ Wg, ushort* __restrict__ dst) {
  int i = blockIdx.x * 256 + threadIdx.x;
  if (i >= KVGW * 2048) return;
  int n = i >> 11, k = i & 2047;
  float v;
  if (n < 128) v = Wk[(size_t)n * 2048 + k];
  else if (n < 256) v = Wv[(size_t)(n - 128) * 2048 + k];
  else if (n < 259) v = Wg[(size_t)(n - 256) * 2048 + k];
  else v = 0.f;
  dst[i] = f2bf(v);
}

// vt[g][d][*] bf16 from kvg v-part (v is NOT roped), with an 8B-slot
// permutation baked into each 64-key block: key k of block blk is stored at
// blk*64 + ((k>>2)^(d&15))*4 + (k&3). mfma_attn stages rows LINEARLY and
// reads slot (kt*4+quad)^l16 -> 16 distinct slots per 16-lane LDS phase =
// bank-conflict-free b64 reads (verified: 6.39M conflicts -> 0 in round 7).
__global__ __launch_bounds__(256) void cvt_vt(const float* __restrict__ kvg,
                                              ushort* __restrict__ vt) {
  int i = blockIdx.x * 256 + threadIdx.x;
  if (i >= T_SEQ * NG * HD) return;
  int d = i & 63, g = (i >> 6) & 1, s = i >> 7;
  int blk = s >> 6, k = s & 63;
  int snew = blk * 64 + (((k >> 2) ^ (d & 15)) << 2) + (k & 3);
  vt[((size_t)g * HD + d) * T_SEQ + snew] =
      f2bf(kvg[(size_t)s * KVGW + 128 + g * 64 + d]);
}

// ------- RoPE: q fp32 -> qbf bf16 PRE-SCALED by 1/8 (exact exponent shift,
// lossless in bf16; lets attention kernels drop the per-score SCALE mul).
// kvg k-part roped in place + kbf bf16 (NOT scaled).
__global__ __launch_bounds__(256) void rope_all(
    const float* __restrict__ q, float* __restrict__ kvg,
    ushort* __restrict__ qbf, ushort* __restrict__ kbf) {
  const int t = blockIdx.x;
  const float lnb_over = 9.210340371976184f / 32.f;  // ln(10000)/32
  for (int job = threadIdx.x; job < (NHQ + NG) * 32; job += 256) {
    int h = job >> 5, j = job & 31;
    float inv = expf(-(float)j * lnb_over);
    float fr = (float)t * inv;
    float c_ = cosf(fr), s_ = sinf(fr);
    if (h < NHQ) {
      const float cq = c_ * 0.125f, sq = s_ * 0.125f;
      const float* base = q + ((size_t)t * NHQ + h) * HD;
      float x1 = base[j], x2 = base[j + 32];
      ushort* ob = qbf + ((size_t)t * NHQ + h) * HD;
      ob[j] = f2bf(x1 * cq - x2 * sq);
      ob[j + 32] = f2bf(x2 * cq + x1 * sq);
    } else {
      int g = h - NHQ;
      float* base = kvg + (size_t)t * KVGW + g * 64;
      float x1 = base[j], x2 = base[j + 32];
      float o1 = x1 * c_ - x2 * s_, o2 = x2 * c_ + x1 * s_;
      base[j] = o1; base[j + 32] = o2;
      kbf[(size_t)t * 128 + g * 64 + j] = f2bf(o1);
      kbf[(size_t)t * 128 + g * 64 + j + 32] = f2bf(o2);
    }
  }
}

// ------- compression: bf16 ck[c][g][d] and transposed bf16 cv^T[g][d][c] ---
// grid (128, 2); c==127 writes the zero pad row (c is padded 127 -> 128).
__global__ __launch_bounds__(256) void compress_kv(
    const float* __restrict__ kvg,
    const float* __restrict__ Wck, const float* __restrict__ Wcv,
    ushort* __restrict__ ck16, ushort* __restrict__ cvt16) {
  const int c = blockIdx.x, g = blockIdx.y;
  const int tid = threadIdx.x;
  if (c == 127) {  // zero pad so MFMA never touches garbage
    if (tid < 64) ck16[((size_t)127 * NG + g) * HD + tid] = 0;
    else if (tid < 128) cvt16[((size_t)g * HD + (tid - 64)) * 128 + 127] = 0;
    return;
  }
  const int d = tid & 63, chunk = tid >> 6;
  __shared__ float red[2][4][64];
  float ak = 0.f, av = 0.f;
  for (int f = chunk * 512; f < chunk * 512 + 512; ++f) {
    int i = f >> 6, e = f & 63;
    int trow = c * CSTRIDE + i;
    float kv = kvg[(size_t)trow * KVGW + g * 64 + e];
    float vv = kvg[(size_t)trow * KVGW + 128 + g * 64 + e];
    ak += kv * Wck[((size_t)g * 2048 + f) * HD + d];
    av += vv * Wcv[((size_t)g * 2048 + f) * HD + d];
  }
  red[0][chunk][d] = ak;
  red[1][chunk][d] = av;
  __syncthreads();
  if (tid < 64) {
    ck16[((size_t)c * NG + g) * HD + tid] =
        f2bf(red[0][0][tid] + red[0][1][tid] + red[0][2][tid] + red[0][3][tid]);
  } else if (tid < 128) {
    int dd = tid - 64;
    cvt16[((size_t)g * HD + dd) * 128 + c] =
        f2bf(red[1][0][dd] + red[1][1][dd] + red[1][2][dd] + red[1][3][dd]);
  }
}

// ------- MFMA compressed attention + block scores + parallel top-16 -------
// grid (128 t-tiles of 16, 2 g), 512 threads = 8 waves x 2 heads each.
// q is pre-scaled by 1/8 (rope_all). tb reversed (LPT: long jobs first).
__global__ __launch_bounds__(512) void comp_attn(
    const ushort* __restrict__ qbf, const ushort* __restrict__ ck16,
    const ushort* __restrict__ cvt16, const float* __restrict__ kvg,
    float* __restrict__ comb, unsigned* __restrict__ sel) {
  const int tb = 127 - blockIdx.x, g = blockIdx.y;  // LPT tail packing
  const int t0 = tb * 16;
  const int tid = threadIdx.x, lane = tid & 63, w = tid >> 6;
  const int quad = lane >> 4, l16 = lane & 15;
  const int qb = t0 >> 6;  // uniform across the 16 t's of this block

  __shared__ float colsum[16][129];  // [t_local][c], padded vs bank conflicts
  for (int i = tid; i < 16 * 129; i += 512) ((float*)colsum)[i] = 0.f;
  __syncthreads();

  const int t = t0 + l16;
  const int cmaxv = (t >= 31) ? min(126, (t - 31) >> 4) : -1;
  const int h0 = w * 2;  // two heads per wave

  short8_t qB[2][2];
  #pragma unroll
  for (int hh = 0; hh < 2; ++hh)
    #pragma unroll
    for (int kd = 0; kd < 2; ++kd)
      qB[hh][kd] = *(const short8_t*)(qbf +
          ((size_t)t * NHQ + g * 16 + h0 + hh) * HD + kd * 32 + quad * 8);

  const f32x4 fz = {0.f, 0.f, 0.f, 0.f};
  f32x4 sp[2][8];

  #pragma unroll
  for (int ct = 0; ct < 8; ++ct) {
    const ushort* kr = ck16 + ((size_t)(ct * 16 + l16) * NG + g) * HD + quad * 8;
    short8_t kA0 = *(const short8_t*)kr;
    short8_t kA1 = *(const short8_t*)(kr + 32);
    #pragma unroll
    for (int hh = 0; hh < 2; ++hh) {
      f32x4 c0 = __builtin_amdgcn_mfma_f32_16x16x32_bf16(kA0, qB[hh][0], fz, 0, 0, 0);
      sp[hh][ct] = __builtin_amdgcn_mfma_f32_16x16x32_bf16(kA1, qB[hh][1], c0, 0, 0, 0);
    }
  }

  short4_t pB[2][8];
  #pragma unroll
  for (int hh = 0; hh < 2; ++hh) {
    float mx = -INFINITY;
    #pragma unroll
    for (int ct = 0; ct < 8; ++ct)
      #pragma unroll
      for (int r = 0; r < 4; ++r) {
        int c = ct * 16 + quad * 4 + r;
        float s_ = (c <= cmaxv) ? sp[hh][ct][r] : -INFINITY;
        sp[hh][ct][r] = s_;
        mx = fmaxf(mx, s_);
      }
    mx = fmaxf(mx, __shfl_xor(mx, 16));
    mx = fmaxf(mx, __shfl_xor(mx, 32));
    if (mx == -INFINITY) mx = 0.f;  // fully-masked rows (t < 31)
    float ls = 0.f;
    #pragma unroll
    for (int ct = 0; ct < 8; ++ct)
      #pragma unroll
      for (int r = 0; r < 4; ++r) {
        float p = __expf(sp[hh][ct][r] - mx);
        sp[hh][ct][r] = p;
        ls += p;
      }
    ls += __shfl_xor(ls, 16);
    ls += __shfl_xor(ls, 32);
    float inv = (ls > 0.f) ? 1.f / ls : 0.f;
    #pragma unroll
    for (int ct = 0; ct < 8; ++ct) {
      short4_t pk;
      #pragma unroll
      for (int r = 0; r < 4; ++r) {
        float pn = sp[hh][ct][r] * inv;
        sp[hh][ct][r] = pn;
        pk[r] = (short)f2bf(pn);
      }
      pB[hh][ct] = pk;
    }
  }

  #pragma unroll
  for (int ct = 0; ct < 8; ++ct)
    #pragma unroll
    for (int r = 0; r < 4; ++r)
      atomicAdd(&colsum[l16][ct * 16 + quad * 4 + r],
                sp[0][ct][r] + sp[1][ct][r]);

  f32x4 acc[2][4];
  #pragma unroll
  for (int hh = 0; hh < 2; ++hh)
    #pragma unroll
    for (int dt = 0; dt < 4; ++dt) acc[hh][dt] = fz;
  #pragma unroll
  for (int ct = 0; ct < 8; ++ct) {
    short4_t vA[4];
    #pragma unroll
    for (int dt = 0; dt < 4; ++dt)
      vA[dt] = *(const short4_t*)(cvt16 +
          ((size_t)g * HD + dt * 16 + l16) * 128 + ct * 16 + quad * 4);
    #pragma unroll
    for (int hh = 0; hh < 2; ++hh)
      #pragma unroll
      for (int dt = 0; dt < 4; ++dt)
        acc[hh][dt] = __builtin_amdgcn_mfma_f32_16x16x16bf16_1k(
            vA[dt], pB[hh][ct], acc[hh][dt], 0, 0, 0);
  }

  const float g0 = 1.f / (1.f + __expf(-kvg[(size_t)t * KVGW + 256]));
  #pragma unroll
  for (int hh = 0; hh < 2; ++hh)
    #pragma unroll
    for (int dt = 0; dt < 4; ++dt)
      #pragma unroll
      for (int r = 0; r < 4; ++r)
        comb[((size_t)t * NHQ + g * 16 + h0 + hh) * HD + dt * 16 + quad * 4 + r] =
            g0 * acc[hh][dt][r];

  __syncthreads();

  {
    const int tl = tid >> 5;   // 0..15
    const int b = tid & 31;
    float s;
    if (b > qb) s = -INFINITY;
    else if (b == 0 || qb - b < 2) s = INFINITY;
    else {
      s = 0.f;
      #pragma unroll
      for (int i = 0; i < 5; ++i) s += colsum[tl][4 * b - 1 + i];
    }
    unsigned key = (s < 0.f) ? 0u : (__float_as_uint(s) + 1u);
    unsigned msel = 0;
    for (int it = 0; it < 16; ++it) {
      unsigned long long pk =
          (((unsigned long long)key) << 6) | (unsigned)(63 - b);
      #pragma unroll
      for (int off = 16; off >= 1; off >>= 1) {
        unsigned long long o = __shfl_xor(pk, off);
        if (o > pk) pk = o;
      }
      if ((pk >> 6) == 0) break;  // uniform within the 32-group
      int bs = 63 - (int)(pk & 63);
      msel |= 1u << bs;
      if (b == bs) key = 0;
    }
    if (b == 0) sel[(size_t)(t0 + tl) * NG + g] = msel;
  }
}

// ------- MFMA flash attention v8: identical math/layout to v7, plus LPT
// scheduling: qb = 31 - blockIdx.x so the LONGEST jobs (high qb, long block
// lists) dispatch first and short ones pack the tail — round-7 occupancy was
// 26% purely from tail imbalance (dispatch order is x-fastest, z-slowest).
// grid (32 qb, 2 g, 16 = 8 hgp x 2 mode). (512,2): 128-VGPR cap, no spill.
__global__ __launch_bounds__(512, 2) void mfma_attn(
    const ushort* __restrict__ qb16, const ushort* __restrict__ kb16,
    const ushort* __restrict__ vtb, const float* __restrict__ kvg,
    const unsigned* __restrict__ sel, float* __restrict__ comb1,
    float* __restrict__ comb2) {
  const int qb = 31 - blockIdx.x, g = blockIdx.y;  // LPT tail packing
  const int hgp = blockIdx.z & 7, mode = blockIdx.z >> 3;
  const int tid = threadIdx.x, lane = tid & 63, w = tid >> 6;  // 8 waves
  const int quad = lane >> 4, l16 = lane & 15;
  const int head = g * 16 + hgp * 2 + (w >> 2);
  const int t0 = qb * 64;

  __shared__ __align__(16) ushort Ks[2][64 * 64];  // 16 KB (dbuf)
  __shared__ __align__(16) ushort Vs[2][64 * 64];  // 16 KB (dbuf)
  __shared__ unsigned sel_s[64];

  if (tid < 64) sel_s[tid] = sel[(size_t)(t0 + tid) * NG + g];
  __syncthreads();

  // my 16 queries (one 16-row tile per wave)
  const int qg = t0 + (w & 3) * 16 + l16;
  const unsigned sbq = sel_s[(w & 3) * 16 + l16];

  short8_t qB0 = *(const short8_t*)(qb16 +
      ((size_t)qg * NHQ + head) * HD + quad * 8);
  short8_t qB1 = *(const short8_t*)(qb16 +
      ((size_t)qg * NHQ + head) * HD + 32 + quad * 8);

  float m_ = -1e30f;
  f32x4 acc[4], accL;
  const f32x4 fz = {0.f, 0.f, 0.f, 0.f};
  #pragma unroll
  for (int dt = 0; dt < 4; ++dt) acc[dt] = fz;
  accL = fz;
  const short4_t onesA = {(short)0x3F80, (short)0x3F80,
                          (short)0x3F80, (short)0x3F80};  // bf16 1.0 x4

  // full key-block list (same for all 8 waves)
  unsigned mrem = 0; int b0 = 0, nb = 0;
  if (mode == 0) {
    unsigned uni = sel_s[lane];  // wave-parallel union OR-reduce
    #pragma unroll
    for (int off = 32; off >= 1; off >>= 1) uni |= __shfl_xor(uni, off);
    mrem = uni;
    nb = __popc(mrem);
  } else {
    b0 = (qb > 8) ? qb - 8 : 0;
    nb = qb - b0 + 1;
  }

  // stage K (XOR 16B chunk swizzle) and V^T (LINEAR — perm is pre-baked in
  // vtb's global layout) into LDS: 1 K-chunk + 1 V-chunk (16B) per thread.
  #define STAGE(buf, blk)                                                     \
    {                                                                         \
      const int blk_ = (blk);                                                 \
      const int row = tid >> 3, cl = tid & 7;                                 \
      const int kck = cl ^ (row & 7);                                         \
      glds16(kb16 + (size_t)(blk_ * 64 + row) * 128 + g * 64 + kck * 8,       \
             &Ks[buf][tid * 8]);                                              \
      glds16(vtb + ((size_t)g * 64 + row) * 2048 + blk_ * 64 + cl * 8,        \
             &Vs[buf][tid * 8]);                                              \
    }

  int blkcur;
  if (mode == 0) { blkcur = __ffs(mrem) - 1; mrem &= mrem - 1; }
  else blkcur = b0;
  STAGE(0, blkcur);
  __syncthreads();  // drains vmcnt(0): tile 0 resident

  const int e = l16 & 7;  // K-read perm (rows = 0 mod 16)

  for (int ib = 0; ib < nb; ++ib) {
    const int cur = ib & 1;
    const int blk = blkcur;
    if (ib + 1 < nb) {  // prefetch next tile into other buffer
      if (mode == 0) { blkcur = __ffs(mrem) - 1; mrem &= mrem - 1; }
      else blkcur = b0 + ib + 1;
      STAGE(cur ^ 1, blkcur);
    }

    // S^T = K Q^T from LDS (swizzled reads; 16B aligned)
    f32x4 sp[4];
    __builtin_amdgcn_s_setprio(1);
    #pragma unroll
    for (int kt = 0; kt < 4; ++kt) {
      const ushort* kr = &Ks[cur][(kt * 16 + l16) * 64];
      short8_t kA0 = *(const short8_t*)(kr + ((quad ^ e) * 8));
      short8_t kA1 = *(const short8_t*)(kr + ((quad ^ e ^ 4) * 8));
      f32x4 c = __builtin_amdgcn_mfma_f32_16x16x32_bf16(kA0, qB0, fz, 0, 0, 0);
      sp[kt] = __builtin_amdgcn_mfma_f32_16x16x32_bf16(kA1, qB1, c, 0, 0, 0);
    }
    __builtin_amdgcn_s_setprio(0);

    const bool diag = (blk == qb);                     // causal mask needed
    const bool wedge = (mode == 1) && (blk == qb - 8); // window-edge mask
    const bool selq = (mode != 0) || (((sbq >> blk) & 1u) != 0);

    float mx = -INFINITY;
    if (!diag && !wedge) {
      // whole 64-key block valid iff selq (uniform across this query's keys)
      #pragma unroll
      for (int kt = 0; kt < 4; ++kt)
        #pragma unroll
        for (int r = 0; r < 4; ++r) {
          float s_ = selq ? sp[kt][r] : -INFINITY;  // q pre-scaled: no mul
          sp[kt][r] = s_;
          mx = fmaxf(mx, s_);
        }
    } else {
      #pragma unroll
      for (int kt = 0; kt < 4; ++kt)
        #pragma unroll
        for (int r = 0; r < 4; ++r) {
          int key = blk * 64 + kt * 16 + quad * 4 + r;
          bool ok = selq && (key <= qg) && (qg - key <= 512);
          float s_ = ok ? sp[kt][r] : -INFINITY;
          sp[kt][r] = s_;
          mx = fmaxf(mx, s_);
        }
    }
    mx = fmaxf(mx, __shfl_xor(mx, 16));
    mx = fmaxf(mx, __shfl_xor(mx, 32));
    float mold = m_;
    if (!__all(mx <= mold + 8.f)) {  // T13 defer-max: rescale rarely
      float mnew = fmaxf(mold, mx);
      float alpha = __expf(mold - mnew);
      #pragma unroll
      for (int dt = 0; dt < 4; ++dt)
        #pragma unroll
        for (int r = 0; r < 4; ++r) acc[dt][r] *= alpha;
      #pragma unroll
      for (int r = 0; r < 4; ++r) accL[r] *= alpha;
      m_ = mnew;
      mold = mnew;
    }
    short4_t pB[4];
    #pragma unroll
    for (int kt = 0; kt < 4; ++kt) {
      float p0 = __expf(sp[kt][0] - mold);  // exp(-inf)=0; p <= e^8
      float p1 = __expf(sp[kt][1] - mold);
      float p2 = __expf(sp[kt][2] - mold);
      float p3 = __expf(sp[kt][3] - mold);
      union { unsigned u[2]; short4_t s; } pk;
      asm("v_cvt_pk_bf16_f32 %0, %1, %2" : "=v"(pk.u[0]) : "v"(p0), "v"(p1));
      asm("v_cvt_pk_bf16_f32 %0, %1, %2" : "=v"(pk.u[1]) : "v"(p2), "v"(p3));
      pB[kt] = pk.s;
    }

    // O^T += V^T P^T from LDS; l-sum via ones-row MFMA (all lanes get total)
    __builtin_amdgcn_s_setprio(1);
    #pragma unroll
    for (int kt = 0; kt < 4; ++kt) {
      #pragma unroll
      for (int dt = 0; dt < 4; ++dt) {
        short4_t vA = *(const short4_t*)(&Vs[cur][(dt * 16 + l16) * 64 +
                                                  (((kt * 4 + quad) ^ l16) << 2)]);
        acc[dt] = __builtin_amdgcn_mfma_f32_16x16x16bf16_1k(
            vA, pB[kt], acc[dt], 0, 0, 0);
      }
      accL = __builtin_amdgcn_mfma_f32_16x16x16bf16_1k(
          onesA, pB[kt], accL, 0, 0, 0);
    }
    __builtin_amdgcn_s_setprio(0);

    __syncthreads();  // all reads of buf[cur] done; next STAGE may overwrite
  }
  #undef STAGE

  // epilogue: each wave owns its 16 queries — no merge needed
  const float l_ = accL[0];
  const float c_ =
      (1.f / (1.f + __expf(-kvg[(size_t)qg * KVGW + 257 + mode]))) / l_;
  #pragma unroll
  for (int dt = 0; dt < 4; ++dt)
    #pragma unroll
    for (int r = 0; r < 4; ++r) {
      const int d = dt * 16 + quad * 4 + r;
      size_t idx = ((size_t)qg * NHQ + head) * HD + d;
      if (mode == 0) comb1[idx] += c_ * acc[dt][r];
      else           comb2[idx]  = c_ * acc[dt][r];
    }
}

extern "C" void kernel_launch(void* const* d_in, const int* in_sizes, int n_in,
                              void* d_out, int out_size, void* d_ws, size_t ws_size,
                              hipStream_t stream) {
  const float* x   = (const float*)d_in[0];
  const float* Wq  = (const float*)d_in[1];
  const float* Wk  = (const float*)d_in[2];
  const float* Wv  = (const float*)d_in[3];
  const float* Wo  = (const float*)d_in[4];
  const float* Wg  = (const float*)d_in[5];
  const float* Wck = (const float*)d_in[6];
  const float* Wcv = (const float*)d_in[7];
  float* out = (float*)d_out;
  float* ws = (float*)d_ws;

  float* qbuf   = ws;                           // 4,194,304 f
  float* comb1  = qbuf + 4194304;               // 4,194,304 f
  float* kvg    = comb1 + 4194304;              //   786,432 f
  float* ckb    = kvg + 786432;                 //    16,384 f (bf16 ck+cvT)
  float* cvb    = ckb + 16384;                  //    16,384 f (unused)
  unsigned* sel = (unsigned*)(cvb + 16384);     //     4,096 u32
  ushort* kbf   = (ushort*)(sel + 4096);        //   262,144 u16
  ushort* vtb   = kbf + 262144;                 //   262,144 u16
  ushort* wkvgb = vtb + 262144;                 //   786,432 u16
  ushort* regA  = wkvgb + 786432;               // 4,194,304 u16: xb -> combb
  ushort* regB  = regA + 4194304;               // 4,194,304 u16: wqb -> qbf
  ushort* xb = regA;      ushort* combb = regA;
  ushort* wqb = regB;     ushort* qbf = regB;
  float* comb2 = qbuf;                // fp32 q dead after rope_all
  ushort* wob = (ushort*)qbuf;        // written after comb2 consumed

  ushort* ckb16 = (ushort*)ckb;       // 128*2*64 u16 = 32 KB
  ushort* cvtb  = ckb16 + 16384;      // 2*64*128 u16 = 32 KB (within ckb slot)

  const int CV4 = (1048576 + 255) / 256;  // 4M elems / 4 per thread
  cvt_bf<<<CV4, 256, 0, stream>>>(x, xb, 4194304);
  cvt_bf<<<CV4, 256, 0, stream>>>(Wq, wqb, 4194304);
  pack_wkvg<<<(KVGW * 2048 + 255) / 256, 256, 0, stream>>>(Wk, Wv, Wg, wkvgb);

  mgemm<<<dim3(32, 16), 256, 0, stream>>>(xb, wqb, qbuf, 2048, 2048, 2048);
  mgemm<<<dim3(6, 16), 256, 0, stream>>>(xb, wkvgb, kvg, 2048, KVGW, 2048);

  rope_all<<<2048, 256, 0, stream>>>(qbuf, kvg, qbf, kbf);
  cvt_vt<<<(262144 + 255) / 256, 256, 0, stream>>>(kvg, vtb);
  compress_kv<<<dim3(128, 2), 256, 0, stream>>>(kvg, Wck, Wcv, ckb16, cvtb);
  comp_attn<<<dim3(128, 2), 512, 0, stream>>>(qbf, ckb16, cvtb, kvg, comb1, sel);
  mfma_attn<<<dim3(32, 2, 16), 512, 0, stream>>>(qbf, kbf, vtb, kvg, sel, comb1, comb2);

  cvt_sum2_bf<<<CV4, 256, 0, stream>>>(comb1, comb2, combb, 4194304);
  cvt_bf<<<CV4, 256, 0, stream>>>(Wo, wob, 4194304);
  mgemm<<<dim3(32, 16), 256, 0, stream>>>(combb, wob, out, 2048, 2048, 2048);
}